// Round 2
// baseline (475.961 us; speedup 1.0000x reference)
//
#include <hip/hip_runtime.h>

// ---------------- problem constants ----------------
#define HID   2048
#define NHEAD 16
#define HD    128
#define SEQ   2048
#define BATCH 2
#define MROWS (BATCH*SEQ)        // 4096
#define NQKV  (3*HID)            // 6144
#define INV_NORM 0.08838834764831845f
#define LOG2E    1.4426950408889634f
#define SCALE_L2 (INV_NORM*LOG2E)

typedef __attribute__((ext_vector_type(8)))  __bf16 bf16x8;
typedef __attribute__((ext_vector_type(4)))  float  f32x4;
typedef __attribute__((ext_vector_type(16))) float  f32x16;

typedef __attribute__((address_space(1))) void GV;
typedef __attribute__((address_space(3))) void LV;

__device__ __forceinline__ void async16(const void* g, void* l) {
  __builtin_amdgcn_global_load_lds((const GV*)g, (LV*)l, 16, 0, 0);
}

__device__ __forceinline__ unsigned short f2bf(float f) {
  unsigned u = __builtin_bit_cast(unsigned, f);
  u += 0x7FFFu + ((u >> 16) & 1u);       // RNE
  return (unsigned short)(u >> 16);
}

__device__ __forceinline__ unsigned pkbf(float a, float b) {
#if __has_builtin(__builtin_amdgcn_cvt_pk_bf16_f32)
  typedef __attribute__((ext_vector_type(2))) __bf16 bf16x2;
  bf16x2 r = __builtin_amdgcn_cvt_pk_bf16_f32(a, b);
  return __builtin_bit_cast(unsigned, r);
#else
  return (unsigned)f2bf(a) | ((unsigned)f2bf(b) << 16);
#endif
}

__device__ __forceinline__ void mfma16(f32x4& c, bf16x8 a, bf16x8 b) {
  c = __builtin_amdgcn_mfma_f32_16x16x32_bf16(a, b, c, 0, 0, 0);
}

// LDS fragment read with chunk-XOR swizzle (BK=64 -> 8 chunks of 16B per row)
__device__ __forceinline__ bf16x8 frag(const unsigned short* buf, int row, int chunk) {
  return *(const bf16x8*)(buf + ((row * 8 + (chunk ^ (row & 7))) << 3));
}

// ---------------- fp32 -> bf16 casts ----------------
__global__ __launch_bounds__(256) void cvt_kernel(const float* __restrict__ src,
                                                  unsigned short* __restrict__ dst, int n) {
  int i = (blockIdx.x * 256 + threadIdx.x) * 4;
  if (i >= n) return;
  float4 v = *(const float4*)(src + i);
  ushort4 o;
  o.x = f2bf(v.x); o.y = f2bf(v.y); o.z = f2bf(v.z); o.w = f2bf(v.w);
  *(ushort4*)(dst + i) = o;
}

__global__ __launch_bounds__(256) void cvtw_kernel(const float* __restrict__ W0,
                                                   const float* __restrict__ W1,
                                                   const float* __restrict__ W2,
                                                   const float* __restrict__ W3,
                                                   unsigned short* __restrict__ dst) {
  int sel = blockIdx.y;
  const float* src = (sel == 0) ? W0 : (sel == 1) ? W1 : (sel == 2) ? W2 : W3;
  unsigned short* d = dst + (size_t)sel * HID * HID;
  int i = (blockIdx.x * 256 + threadIdx.x) * 4;
  float4 v = *(const float4*)(src + i);
  ushort4 o;
  o.x = f2bf(v.x); o.y = f2bf(v.y); o.z = f2bf(v.z); o.w = f2bf(v.w);
  *(ushort4*)(d + i) = o;
}

// ---------------- 128x128 NT GEMM core (kept for gemm_out) ----------------
__device__ __forceinline__ void gemm_core(const unsigned short* __restrict__ A,
                                          const unsigned short* __restrict__ Bm,
                                          int K, int m0, int n0,
                                          unsigned short* As, unsigned short* Bs,
                                          f32x4 (&acc)[4][4]) {
  const int tid  = threadIdx.x;
  const int w    = tid >> 6;
  const int lane = tid & 63;
  const int l16  = lane & 15;
  const int quad = lane >> 4;
  const int wm   = (w & 1) * 64;
  const int wn   = (w >> 1) * 64;

  const f32x4 zero = {0.f, 0.f, 0.f, 0.f};
#pragma unroll
  for (int i = 0; i < 4; ++i)
#pragma unroll
    for (int j = 0; j < 4; ++j) acc[i][j] = zero;

  for (int k0 = 0; k0 < K; k0 += 64) {
    __syncthreads();
#pragma unroll
    for (int i = 0; i < 4; ++i) {
      int slot = i * 256 + w * 64 + lane;
      int r = slot >> 3;
      int c = (slot & 7) ^ (r & 7);
      async16(A  + (size_t)(m0 + r) * K + k0 + c * 8, (char*)As + (size_t)(i * 256 + w * 64) * 16);
      async16(Bm + (size_t)(n0 + r) * K + k0 + c * 8, (char*)Bs + (size_t)(i * 256 + w * 64) * 16);
    }
    __syncthreads();

#pragma unroll
    for (int kk = 0; kk < 2; ++kk) {
      bf16x8 af[4], bfp[4];
#pragma unroll
      for (int i = 0; i < 4; ++i) af[i]  = frag(As, wm + i * 16 + l16, kk * 4 + quad);
#pragma unroll
      for (int j = 0; j < 4; ++j) bfp[j] = frag(Bs, wn + j * 16 + l16, kk * 4 + quad);
#pragma unroll
      for (int i = 0; i < 4; ++i)
#pragma unroll
        for (int j = 0; j < 4; ++j) mfma16(acc[i][j], af[i], bfp[j]);
    }
  }
}

// ---------------- GEMM 1: QKV projection, 256x256 8-phase, deep counted-vmcnt ----------------
// 512 thr = 8 waves (2M x 4N); per-wave C = 128x64; BK=64; LDS 128 KiB (2 dbuf x (A+B)).
// buf0 <-> even K-tiles, buf1 <-> odd K-tiles. 2 K-tiles / iteration, 8 phases.
// Panel liveness (per iteration): buf0.B + buf0.A{0,128} dead after P2; buf0.A{64,192}
// dead after P4; buf1.B + buf1.A{0,128} dead after P6; buf1.A{64,192} dead after P8.
// STG issue: P1: o.A64,A192 | P3: e'.A0,A128,B0 | P4: e'.B64,B128,B192 | P5: e'.A64,A192
//            P7: o'.A0,A128,B0 | P8: o'.B64,B128,B192   (e'=2i+2, o'=2i+3, o=2i+1)
// Waits: vmcnt(8) at end of P2/P4/P6/P8 -> every waited load has >=4 phases of latency
// coverage; 8-14 loads always in flight (never drains below 8).
#define ASZ (256 * 64)

__global__ __launch_bounds__(512, 2) void gemm_qkv256_kernel(
    const unsigned short* __restrict__ Xb, const unsigned short* __restrict__ Wb,
    const float* __restrict__ bq, const float* __restrict__ bk,
    const float* __restrict__ bv, unsigned short* __restrict__ Cout) {
  __shared__ __align__(16) unsigned short As[2 * ASZ];   // 64 KiB
  __shared__ __align__(16) unsigned short Bs[2 * ASZ];   // 64 KiB

  const int tid  = threadIdx.x;
  const int w    = tid >> 6;
  const int lane = tid & 63;
  const int l16  = lane & 15;
  const int quad = lane >> 4;
  const int wm   = (w & 1) * 128;
  const int wn   = (w >> 1) * 64;

  // XCD-swizzled tile mapping; grid = 384 = 16(m) x 24(n), 384 % 8 == 0 -> bijective
  const int wg = blockIdx.x;
  const int sw = (wg & 7) * 48 + (wg >> 3);
  const int m0 = (sw & 15) * 256;
  const int n0 = (sw >> 4) * 256;

  const unsigned short* Ag = Xb + (size_t)m0 * HID;
  const unsigned short* Bg = Wb + (size_t)n0 * HID;

  // staging: one STG = 512 lanes x 16B = 8 KiB = one 64-row panel; LDS dest linear,
  // global source chunk pre-swizzled (inverse of frag()'s read swizzle)
  const int sr  = tid >> 3;                    // local row 0..63 in panel
  const int scs = ((tid & 7) ^ (sr & 7)) * 8;  // swizzled source chunk offset (ushorts)

#define STG(SRC, DST, RB, KO)                                        \
  async16((SRC) + (size_t)((RB) + sr) * HID + (KO) + scs,            \
          (char*)(DST) + (((RB) * 8 + w * 64) * 16))

  f32x4 acc[8][4];
  const f32x4 zero = {0.f, 0.f, 0.f, 0.f};
#pragma unroll
  for (int a = 0; a < 8; ++a)
#pragma unroll
    for (int j = 0; j < 4; ++j) acc[a][j] = zero;

  // prologue: tile0 (ih0+B first, then ih1-A) -> buf0; tile1 all 6 early panels+late -> buf1
  STG(Ag, As, 0, 0);   STG(Ag, As, 128, 0);
  STG(Bg, Bs, 0, 0);   STG(Bg, Bs, 64, 0);  STG(Bg, Bs, 128, 0);  STG(Bg, Bs, 192, 0);
  STG(Ag, As, 64, 0);  STG(Ag, As, 192, 0);
  STG(Ag, As + ASZ, 0, 64);   STG(Ag, As + ASZ, 128, 64);  STG(Bg, Bs + ASZ, 0, 64);
  STG(Bg, Bs + ASZ, 64, 64);  STG(Bg, Bs + ASZ, 128, 64);  STG(Bg, Bs + ASZ, 192, 64);
  asm volatile("s_waitcnt vmcnt(8)" ::: "memory");   // t0 ih0+B landed; 8 in flight
  __builtin_amdgcn_s_barrier();

  for (int i = 0; i < 16; ++i) {
    const int ko  = (2 * i + 1) * 64;          // tile o (read this iter P5-P8), late A panels
    const int t2  = 2 * i + 2, t3 = 2 * i + 3;
    const int ke  = (t2 < 32 ? t2 : 31) * 64;  // clamp: garbage lands in dead panels
    const int ko2 = (t3 < 32 ? t3 : 31) * 64;
    bf16x8 tb0[4], tb1[4];

    // ---- P1: buf0 kk=0 ih=0 | STG o.A64,A192 -> buf1 ----
    {
      bf16x8 ta[4];
#pragma unroll
      for (int ii = 0; ii < 4; ++ii) ta[ii] = frag(As, wm + ii * 16 + l16, quad);
#pragma unroll
      for (int j = 0; j < 4; ++j) tb0[j] = frag(Bs, wn + j * 16 + l16, quad);
      STG(Ag, As + ASZ, 64, ko);
      STG(Ag, As + ASZ, 192, ko);
      __builtin_amdgcn_s_barrier();
      asm volatile("s_waitcnt lgkmcnt(0)" ::: "memory");
      __builtin_amdgcn_s_setprio(1);
#pragma unroll
      for (int ii = 0; ii < 4; ++ii)
#pragma unroll
        for (int j = 0; j < 4; ++j) mfma16(acc[ii][j], ta[ii], tb0[j]);
      __builtin_amdgcn_s_setprio(0);
      __builtin_amdgcn_s_barrier();
    }
    // ---- P2: buf0 kk=1 ih=0 | no STG | vmcnt(8): e.A64,A192 landed for P3 ----
    {
      bf16x8 ta[4];
#pragma unroll
      for (int ii = 0; ii < 4; ++ii) ta[ii] = frag(As, wm + ii * 16 + l16, 4 + quad);
#pragma unroll
      for (int j = 0; j < 4; ++j) tb1[j] = frag(Bs, wn + j * 16 + l16, 4 + quad);
      __builtin_amdgcn_s_barrier();
      asm volatile("s_waitcnt lgkmcnt(0)" ::: "memory");
      __builtin_amdgcn_s_setprio(1);
#pragma unroll
      for (int ii = 0; ii < 4; ++ii)
#pragma unroll
        for (int j = 0; j < 4; ++j) mfma16(acc[ii][j], ta[ii], tb1[j]);
      __builtin_amdgcn_s_setprio(0);
      asm volatile("s_waitcnt vmcnt(8)" ::: "memory");
      __builtin_amdgcn_s_barrier();
    }
    // ---- P3: buf0 kk=0 ih=1 | STG e'.A0,A128,B0 -> buf0 (dead after P2) | reuse tb0 ----
    {
      bf16x8 ta[4];
#pragma unroll
      for (int ii = 0; ii < 4; ++ii) ta[ii] = frag(As, wm + 64 + ii * 16 + l16, quad);
      STG(Ag, As, 0, ke);
      STG(Ag, As, 128, ke);
      STG(Bg, Bs, 0, ke);
      __builtin_amdgcn_s_barrier();
      asm volatile("s_waitcnt lgkmcnt(0)" ::: "memory");
      __builtin_amdgcn_s_setprio(1);
#pragma unroll
      for (int ii = 0; ii < 4; ++ii)
#pragma unroll
        for (int j = 0; j < 4; ++j) mfma16(acc[4 + ii][j], ta[ii], tb0[j]);
      __builtin_amdgcn_s_setprio(0);
      __builtin_amdgcn_s_barrier();
    }
    // ---- P4: buf0 kk=1 ih=1 | STG e'.B64,B128,B192 | reuse tb1 | vmcnt(8): o early 6 landed ----
    {
      bf16x8 ta[4];
#pragma unroll
      for (int ii = 0; ii < 4; ++ii) ta[ii] = frag(As, wm + 64 + ii * 16 + l16, 4 + quad);
      STG(Bg, Bs, 64, ke);
      STG(Bg, Bs, 128, ke);
      STG(Bg, Bs, 192, ke);
      __builtin_amdgcn_s_barrier();
      asm volatile("s_waitcnt lgkmcnt(0)" ::: "memory");
      __builtin_amdgcn_s_setprio(1);
#pragma unroll
      for (int ii = 0; ii < 4; ++ii)
#pragma unroll
        for (int j = 0; j < 4; ++j) mfma16(acc[4 + ii][j], ta[ii], tb1[j]);
      __builtin_amdgcn_s_setprio(0);
      asm volatile("s_waitcnt vmcnt(8)" ::: "memory");
      __builtin_amdgcn_s_barrier();
    }
    // ---- P5: buf1 kk=0 ih=0 | STG e'.A64,A192 -> buf0 (dead after P4) ----
    {
      bf16x8 ta[4];
#pragma unroll
      for (int ii = 0; ii < 4; ++ii) ta[ii] = frag(As + ASZ, wm + ii * 16 + l16, quad);
#pragma unroll
      for (int j = 0; j < 4; ++j) tb0[j] = frag(Bs + ASZ, wn + j * 16 + l16, quad);
      STG(Ag, As, 64, ke);
      STG(Ag, As, 192, ke);
      __builtin_amdgcn_s_barrier();
      asm volatile("s_waitcnt lgkmcnt(0)" ::: "memory");
      __builtin_amdgcn_s_setprio(1);
#pragma unroll
      for (int ii = 0; ii < 4; ++ii)
#pragma unroll
        for (int j = 0; j < 4; ++j) mfma16(acc[ii][j], ta[ii], tb0[j]);
      __builtin_amdgcn_s_setprio(0);
      __builtin_amdgcn_s_barrier();
    }
    // ---- P6: buf1 kk=1 ih=0 | no STG | vmcnt(8): o.A64,A192 landed for P7 ----
    {
      bf16x8 ta[4];
#pragma unroll
      for (int ii = 0; ii < 4; ++ii) ta[ii] = frag(As + ASZ, wm + ii * 16 + l16, 4 + quad);
#pragma unroll
      for (int j = 0; j < 4; ++j) tb1[j] = frag(Bs + ASZ, wn + j * 16 + l16, 4 + quad);
      __builtin_amdgcn_s_barrier();
      asm volatile("s_waitcnt lgkmcnt(0)" ::: "memory");
      __builtin_amdgcn_s_setprio(1);
#pragma unroll
      for (int ii = 0; ii < 4; ++ii)
#pragma unroll
        for (int j = 0; j < 4; ++j) mfma16(acc[ii][j], ta[ii], tb1[j]);
      __builtin_amdgcn_s_setprio(0);
      asm volatile("s_waitcnt vmcnt(8)" ::: "memory");
      __builtin_amdgcn_s_barrier();
    }
    // ---- P7: buf1 kk=0 ih=1 | STG o'.A0,A128,B0 -> buf1 (dead after P6) | reuse tb0 ----
    {
      bf16x8 ta[4];
#pragma unroll
      for (int ii = 0; ii < 4; ++ii) ta[ii] = frag(As + ASZ, wm + 64 + ii * 16 + l16, quad);
      STG(Ag, As + ASZ, 0, ko2);
      STG(Ag, As + ASZ, 128, ko2);
      STG(Bg, Bs + ASZ, 0, ko2);
      __builtin_amdgcn_s_barrier();
      asm volatile("s_waitcnt lgkmcnt(0)" ::: "memory");
      __builtin_amdgcn_s_setprio(1);
#pragma unroll
      for (int ii = 0; ii < 4; ++ii)
#pragma unroll
        for (int j = 0; j < 4; ++j) mfma16(acc[4 + ii][j], ta[ii], tb0[j]);
      __builtin_amdgcn_s_setprio(0);
      __builtin_amdgcn_s_barrier();
    }
    // ---- P8: buf1 kk=1 ih=1 | STG o'.B64,B128,B192 | reuse tb1 | vmcnt(8): e' early 6 landed ----
    {
      bf16x8 ta[4];
#pragma unroll
      for (int ii = 0; ii < 4; ++ii) ta[ii] = frag(As + ASZ, wm + 64 + ii * 16 + l16, 4 + quad);
      STG(Bg, Bs + ASZ, 64, ko2);
      STG(Bg, Bs + ASZ, 128, ko2);
      STG(Bg, Bs + ASZ, 192, ko2);
      __builtin_amdgcn_s_barrier();
      asm volatile("s_waitcnt lgkmcnt(0)" ::: "memory");
      __builtin_amdgcn_s_setprio(1);
#pragma unroll
      for (int ii = 0; ii < 4; ++ii)
#pragma unroll
        for (int j = 0; j < 4; ++j) mfma16(acc[4 + ii][j], ta[ii], tb1[j]);
      __builtin_amdgcn_s_setprio(0);
      asm volatile("s_waitcnt vmcnt(8)" ::: "memory");
      __builtin_amdgcn_s_barrier();
    }
  }
#undef STG

  // epilogue: bias + bf16 store.  C/D frag: row = quad*4+r, col = l16
#pragma unroll
  for (int j = 0; j < 4; ++j) {
    int ng = n0 + wn + j * 16 + l16;
    float bias = (ng < HID) ? bq[ng] : (ng < 2 * HID ? bk[ng - HID] : bv[ng - 2 * HID]);
#pragma unroll
    for (int a = 0; a < 8; ++a)
#pragma unroll
      for (int r = 0; r < 4; ++r) {
        int mg = m0 + wm + (a >> 2) * 64 + (a & 3) * 16 + quad * 4 + r;
        Cout[(size_t)mg * NQKV + ng] = f2bf(acc[a][j][r] + bias);
      }
  }
}

// ---------------- GEMM 2: out-proj + bias + residual, fp32 out ----------------
__global__ __launch_bounds__(256) void gemm_out_kernel(
    const unsigned short* __restrict__ Ctx, const unsigned short* __restrict__ Wdb,
    const float* __restrict__ bd, const float* __restrict__ Res,
    float* __restrict__ Out) {
  __shared__ __align__(16) unsigned short As[128 * 64];
  __shared__ __align__(16) unsigned short Bs[128 * 64];
  f32x4 acc[4][4];
  const int m0 = blockIdx.y * 128, n0 = blockIdx.x * 128;
  gemm_core(Ctx, Wdb, HID, m0, n0, As, Bs, acc);

  const int tid = threadIdx.x, w = tid >> 6, lane = tid & 63;
  const int l16 = lane & 15, quad = lane >> 4;
  const int wm = (w & 1) * 64, wn = (w >> 1) * 64;
#pragma unroll
  for (int j = 0; j < 4; ++j) {
    int ng = n0 + wn + j * 16 + l16;
    float bias = bd[ng];
#pragma unroll
    for (int i = 0; i < 4; ++i)
#pragma unroll
      for (int r = 0; r < 4; ++r) {
        int mg = m0 + wm + i * 16 + quad * 4 + r;
        size_t off = (size_t)mg * HID + ng;
        Out[off] = acc[i][j][r] + bias + Res[off];
      }
  }
}

// ---------------- V transpose: QKV V-part -> Vt[bh][d][s] ----------------
__global__ __launch_bounds__(256) void vtrans_kernel(const unsigned short* __restrict__ QKV,
                                                     unsigned short* __restrict__ Vt) {
  __shared__ __align__(16) unsigned short T[64][72];
  const int s0 = blockIdx.x * 64, d0 = blockIdx.y * 64, bh = blockIdx.z;
  const int b = bh >> 4, h = bh & 15;
  const int tid = threadIdx.x;
#pragma unroll
  for (int i = 0; i < 2; ++i) {
    int idx = i * 256 + tid;
    int r = idx >> 3, ch = idx & 7;
    const unsigned short* g = QKV + ((size_t)b * SEQ + s0 + r) * NQKV + 2 * HID + h * HD + d0 + ch * 8;
    *(uint4*)(&T[r][ch * 8]) = *(const uint4*)g;
  }
  __syncthreads();
#pragma unroll
  for (int i = 0; i < 2; ++i) {
    int idx = i * 256 + tid;
    int d = idx >> 3, ch = idx & 7;
    unsigned short v[8];
#pragma unroll
    for (int x = 0; x < 8; ++x) v[x] = T[ch * 8 + x][d];
    unsigned short* g = Vt + ((size_t)bh * HD + d0 + d) * SEQ + s0 + ch * 8;
    *(uint4*)g = *(const uint4*)v;
  }
}

// ---------------- flash attention, 32x32 MFMA, S^T trick ----------------
// grid = (SEQ/128, BATCH*NHEAD); block 256 (4 waves, each 32 q-rows)
__global__ __launch_bounds__(256, 2) void attn_kernel(
    const unsigned short* __restrict__ QKV, const unsigned short* __restrict__ Vt,
    const float* __restrict__ alibi, unsigned short* __restrict__ Ctx) {
  __shared__ __align__(16) char smem[51200];
  unsigned short* Ks  = (unsigned short*)smem;
  unsigned short* Vts = (unsigned short*)(smem + 16384);
  unsigned short* Ps  = (unsigned short*)(smem + 32768);
  unsigned short* Qs  = (unsigned short*)smem;          // alias: Q staging (32 KB)

  const int tid = threadIdx.x, w = tid >> 6, lane = tid & 63;
  const int l32 = lane & 31, h = lane >> 5;
  const int q0 = blockIdx.x * 128;
  const int bh = blockIdx.y, b = bh >> 4, hh = bh & 15;
  const size_t rowbase = (size_t)b * SEQ;
  const float* ali = alibi + (size_t)bh * SEQ;
  const unsigned short* Vbh = Vt + (size_t)bh * HD * SEQ;

  {
    const unsigned short* qbase = QKV + (rowbase + q0) * NQKV + hh * HD;
#pragma unroll
    for (int i = 0; i < 8; ++i) {
      int slot = i * 256 + w * 64 + lane;
      int r = slot >> 4, c = (slot & 15) ^ (r & 15);
      async16(qbase + (size_t)r * NQKV + c * 8, (char*)Qs + (size_t)(i * 256 + w * 64) * 16);
    }
  }
  __syncthreads();
  bf16x8 qf[8];
  {
    int qr = w * 32 + l32;
#pragma unroll
    for (int ks = 0; ks < 8; ++ks) {
      int c = (ks * 2 + h) ^ (qr & 15);
      qf[ks] = *(const bf16x8*)(Qs + (qr * 16 + c) * 8);
    }
  }

  f32x16 oacc[4];
  float l_acc = 0.f;
#pragma unroll
  for (int nb = 0; nb < 4; ++nb)
#pragma unroll
    for (int r = 0; r < 16; ++r) oacc[nb][r] = 0.f;

  __syncthreads();

  for (int kt = 0; kt < SEQ / 64; ++kt) {
    {
      const unsigned short* kbase = QKV + (rowbase + kt * 64) * NQKV + HID + hh * HD;
#pragma unroll
      for (int i = 0; i < 4; ++i) {
        int slot = i * 256 + w * 64 + lane;
        int r = slot >> 4, c = (slot & 15) ^ (r & 15);
        async16(kbase + (size_t)r * NQKV + c * 8, (char*)Ks + (size_t)(i * 256 + w * 64) * 16);
      }
      const unsigned short* vbase = Vbh + kt * 64;
#pragma unroll
      for (int i = 0; i < 4; ++i) {
        int slot = i * 256 + w * 64 + lane;
        int r = slot >> 3, c = (slot & 7) ^ (r & 7);
        async16(vbase + (size_t)r * SEQ + c * 8, (char*)Vts + (size_t)(i * 256 + w * 64) * 16);
      }
    }
    __syncthreads();

    f32x16 sacc[2];
#pragma unroll
    for (int mb = 0; mb < 2; ++mb)
#pragma unroll
      for (int r = 0; r < 16; ++r) sacc[mb][r] = 0.f;
#pragma unroll
    for (int ks = 0; ks < 8; ++ks) {
#pragma unroll
      for (int mb = 0; mb < 2; ++mb) {
        bf16x8 kf = *(const bf16x8*)(Ks + ((mb * 32 + l32) * 16 + ((ks * 2 + h) ^ (l32 & 15))) * 8);
        sacc[mb] = __builtin_amdgcn_mfma_f32_32x32x16_bf16(kf, qf[ks], sacc[mb], 0, 0, 0);
      }
    }

    const float* alik = ali + kt * 64 + 4 * h;
    const int qrow = w * 32 + l32;
#pragma unroll
    for (int mb = 0; mb < 2; ++mb) {
#pragma unroll
      for (int g = 0; g < 4; ++g) {
        float4 av = *(const float4*)(alik + mb * 32 + g * 8);
        float p0 = __builtin_amdgcn_exp2f(sacc[mb][g * 4 + 0] * SCALE_L2 + av.x * LOG2E);
        float p1 = __builtin_amdgcn_exp2f(sacc[mb][g * 4 + 1] * SCALE_L2 + av.y * LOG2E);
        float p2 = __builtin_amdgcn_exp2f(sacc[mb][g * 4 + 2] * SCALE_L2 + av.z * LOG2E);
        float p3 = __builtin_amdgcn_exp2f(sacc[mb][g * 4 + 3] * SCALE_L2 + av.w * LOG2E);
        l_acc += (p0 + p1) + (p2 + p3);
        uint2 pk;
        pk.x = pkbf(p0, p1);
        pk.y = pkbf(p2, p3);
        *(uint2*)(Ps + qrow * 72 + mb * 32 + g * 8 + 4 * h) = pk;
      }
    }

#pragma unroll
    for (int ks2 = 0; ks2 < 4; ++ks2) {
      bf16x8 pf = *(const bf16x8*)(Ps + qrow * 72 + ks2 * 16 + h * 8);
#pragma unroll
      for (int nb = 0; nb < 4; ++nb) {
        bf16x8 vf = *(const bf16x8*)(Vts + ((nb * 32 + l32) * 8 + ((ks2 * 2 + h) ^ (l32 & 7))) * 8);
        oacc[nb] = __builtin_amdgcn_mfma_f32_32x32x16_bf16(pf, vf, oacc[nb], 0, 0, 0);
      }
    }
    __syncthreads();
  }

  float lf = l_acc + __shfl_xor(l_acc, 32, 64);
  float rinv[16];
#pragma unroll
  for (int reg = 0; reg < 16; ++reg) {
    int row = (reg & 3) + 8 * (reg >> 2) + 4 * h;
    rinv[reg] = 1.0f / __shfl(lf, row, 64);
  }

#pragma unroll
  for (int nb = 0; nb < 4; ++nb)
#pragma unroll
    for (int reg = 0; reg < 16; ++reg) {
      int row = (reg & 3) + 8 * (reg >> 2) + 4 * h;
      size_t qg = rowbase + q0 + w * 32 + row;
      Ctx[qg * HID + hh * HD + nb * 32 + l32] = f2bf(oacc[nb][reg] * rinv[reg]);
    }
}

// ---------------- launch ----------------
extern "C" void kernel_launch(void* const* d_in, const int* in_sizes, int n_in,
                              void* d_out, int out_size, void* d_ws, size_t ws_size,
                              hipStream_t stream) {
  const float* hidden   = (const float*)d_in[0];
  const float* residual = (const float*)d_in[1];
  const float* alibi    = (const float*)d_in[2];
  const float* Wq = (const float*)d_in[3];
  const float* bq = (const float*)d_in[4];
  const float* Wk = (const float*)d_in[5];
  const float* bk = (const float*)d_in[6];
  const float* Wv = (const float*)d_in[7];
  const float* bv = (const float*)d_in[8];
  const float* Wd = (const float*)d_in[9];
  const float* bd = (const float*)d_in[10];
  float* out = (float*)d_out;

  unsigned short* Xb    = (unsigned short*)d_ws;                    // 4096*2048
  unsigned short* Wqkvb = Xb + (size_t)MROWS * HID;                 // 6144*2048
  unsigned short* Wdb   = Wqkvb + (size_t)NQKV * HID;               // 2048*2048
  unsigned short* QKVb  = Wdb + (size_t)HID * HID;                  // 4096*6144
  unsigned short* Ctxb  = QKVb + (size_t)MROWS * NQKV;              // 4096*2048
  unsigned short* Vtb   = Wqkvb;  // Vt reuses Wqkvb region (dead after gemm_qkv)

  const int nX = MROWS * HID, nW = HID * HID;
  cvt_kernel<<<nX / 4 / 256, 256, 0, stream>>>(hidden, Xb, nX);
  cvtw_kernel<<<dim3(nW / 4 / 256, 4), 256, 0, stream>>>(Wq, Wk, Wv, Wd, Wqkvb);

  gemm_qkv256_kernel<<<384, 512, 0, stream>>>(Xb, Wqkvb, bq, bk, bv, QKVb);
  vtrans_kernel<<<dim3(SEQ / 64, HD / 64, BATCH * NHEAD), 256, 0, stream>>>(QKVb, Vtb);
  attn_kernel<<<dim3(SEQ / 128, BATCH * NHEAD), 256, 0, stream>>>(QKVb, Vtb, alibi, Ctxb);
  gemm_out_kernel<<<dim3(HID / 128, MROWS / 128), 256, 0, stream>>>(Ctxb, Wdb, bd, residual, out);
}

// Round 3
// 449.027 us; speedup vs baseline: 1.0600x; 1.0600x over previous
//
#include <hip/hip_runtime.h>

// ---------------- problem constants ----------------
#define HID   2048
#define NHEAD 16
#define HD    128
#define SEQ   2048
#define BATCH 2
#define MROWS (BATCH*SEQ)        // 4096
#define NQKV  (3*HID)            // 6144
#define INV_NORM 0.08838834764831845f
#define LOG2E    1.4426950408889634f
#define SCALE_L2 (INV_NORM*LOG2E)

typedef __attribute__((ext_vector_type(8)))  __bf16 bf16x8;
typedef __attribute__((ext_vector_type(4)))  float  f32x4;
typedef __attribute__((ext_vector_type(16))) float  f32x16;

typedef __attribute__((address_space(1))) void GV;
typedef __attribute__((address_space(3))) void LV;

__device__ __forceinline__ void async16(const void* g, void* l) {
  __builtin_amdgcn_global_load_lds((const GV*)g, (LV*)l, 16, 0, 0);
}

__device__ __forceinline__ unsigned short f2bf(float f) {
  unsigned u = __builtin_bit_cast(unsigned, f);
  u += 0x7FFFu + ((u >> 16) & 1u);       // RNE
  return (unsigned short)(u >> 16);
}

__device__ __forceinline__ unsigned pkbf(float a, float b) {
#if __has_builtin(__builtin_amdgcn_cvt_pk_bf16_f32)
  typedef __attribute__((ext_vector_type(2))) __bf16 bf16x2;
  bf16x2 r = __builtin_amdgcn_cvt_pk_bf16_f32(a, b);
  return __builtin_bit_cast(unsigned, r);
#else
  return (unsigned)f2bf(a) | ((unsigned)f2bf(b) << 16);
#endif
}

__device__ __forceinline__ void mfma16(f32x4& c, bf16x8 a, bf16x8 b) {
  c = __builtin_amdgcn_mfma_f32_16x16x32_bf16(a, b, c, 0, 0, 0);
}

// LDS fragment read with chunk-XOR swizzle (BK=64 -> 8 chunks of 16B per row)
__device__ __forceinline__ bf16x8 frag(const unsigned short* buf, int row, int chunk) {
  return *(const bf16x8*)(buf + ((row * 8 + (chunk ^ (row & 7))) << 3));
}

// ---------------- fp32 -> bf16 casts ----------------
__global__ __launch_bounds__(256) void cvt_kernel(const float* __restrict__ src,
                                                  unsigned short* __restrict__ dst, int n) {
  int i = (blockIdx.x * 256 + threadIdx.x) * 4;
  if (i >= n) return;
  float4 v = *(const float4*)(src + i);
  ushort4 o;
  o.x = f2bf(v.x); o.y = f2bf(v.y); o.z = f2bf(v.z); o.w = f2bf(v.w);
  *(ushort4*)(dst + i) = o;
}

__global__ __launch_bounds__(256) void cvtw_kernel(const float* __restrict__ W0,
                                                   const float* __restrict__ W1,
                                                   const float* __restrict__ W2,
                                                   const float* __restrict__ W3,
                                                   unsigned short* __restrict__ dst) {
  int sel = blockIdx.y;
  const float* src = (sel == 0) ? W0 : (sel == 1) ? W1 : (sel == 2) ? W2 : W3;
  unsigned short* d = dst + (size_t)sel * HID * HID;
  int i = (blockIdx.x * 256 + threadIdx.x) * 4;
  float4 v = *(const float4*)(src + i);
  ushort4 o;
  o.x = f2bf(v.x); o.y = f2bf(v.y); o.z = f2bf(v.z); o.w = f2bf(v.w);
  *(ushort4*)(d + i) = o;
}

// ---------------- 128x128 NT GEMM core (kept for gemm_out) ----------------
__device__ __forceinline__ void gemm_core(const unsigned short* __restrict__ A,
                                          const unsigned short* __restrict__ Bm,
                                          int K, int m0, int n0,
                                          unsigned short* As, unsigned short* Bs,
                                          f32x4 (&acc)[4][4]) {
  const int tid  = threadIdx.x;
  const int w    = tid >> 6;
  const int lane = tid & 63;
  const int l16  = lane & 15;
  const int quad = lane >> 4;
  const int wm   = (w & 1) * 64;
  const int wn   = (w >> 1) * 64;

  const f32x4 zero = {0.f, 0.f, 0.f, 0.f};
#pragma unroll
  for (int i = 0; i < 4; ++i)
#pragma unroll
    for (int j = 0; j < 4; ++j) acc[i][j] = zero;

  for (int k0 = 0; k0 < K; k0 += 64) {
    __syncthreads();
#pragma unroll
    for (int i = 0; i < 4; ++i) {
      int slot = i * 256 + w * 64 + lane;
      int r = slot >> 3;
      int c = (slot & 7) ^ (r & 7);
      async16(A  + (size_t)(m0 + r) * K + k0 + c * 8, (char*)As + (size_t)(i * 256 + w * 64) * 16);
      async16(Bm + (size_t)(n0 + r) * K + k0 + c * 8, (char*)Bs + (size_t)(i * 256 + w * 64) * 16);
    }
    __syncthreads();

#pragma unroll
    for (int kk = 0; kk < 2; ++kk) {
      bf16x8 af[4], bfp[4];
#pragma unroll
      for (int i = 0; i < 4; ++i) af[i]  = frag(As, wm + i * 16 + l16, kk * 4 + quad);
#pragma unroll
      for (int j = 0; j < 4; ++j) bfp[j] = frag(Bs, wn + j * 16 + l16, kk * 4 + quad);
#pragma unroll
      for (int i = 0; i < 4; ++i)
#pragma unroll
        for (int j = 0; j < 4; ++j) mfma16(acc[i][j], af[i], bfp[j]);
    }
  }
}

// ---------------- GEMM 1: QKV projection, persistent 256-block, 3x(256x128) passes ----
// Grid = 256 blocks (EXACT 1 round on 256 CUs, uniform work -> zero tail).
// Each block owns a 256x384 region = 3 passes of 256x128 (A re-read from L2 per pass).
// 512 thr = 8 waves (2M x 4N); per-wave 128x32; acc[8][2] (64 VGPR); BK=64.
// LDS: 3 rotating buffers x (A 256x64 + B 128x64) = 3 x 48KB = 144KB.
// 4 phases / 2 K-tiles; per phase: 10 ds_read_b128 + 3 global_load_lds + 16 MFMA.
// FIFO-verified waits: vmcnt(6) at end-P2 (drains odd tile) and end-P4 (drains next
// even tile); every waited load issued 3-4 phases earlier; >=6 in flight except the
// peeled last iteration per pass (one vmcnt(0)).
#define BUFU (24576)   // ushorts per buffer (48KB): A 16384 + B 8192
#define BUF3 (3 * BUFU)

__global__ __launch_bounds__(512, 2) void gemm_qkv384_kernel(
    const unsigned short* __restrict__ Xb, const unsigned short* __restrict__ Wb,
    const float* __restrict__ bq, const float* __restrict__ bk,
    const float* __restrict__ bv, unsigned short* __restrict__ Cout) {
  __shared__ __align__(16) unsigned short smem[BUF3];   // 144 KiB

  const int tid  = threadIdx.x;
  const int w    = tid >> 6;
  const int lane = tid & 63;
  const int l16  = lane & 15;
  const int quad = lane >> 4;
  const int wm   = (w & 1) * 128;
  const int wn   = (w >> 1) * 32;

  // XCD-swizzled region mapping; grid = 256 = 16(m) x 16(n-region), 256 % 8 == 0
  const int wg = blockIdx.x;
  const int sw = (wg & 7) * 32 + (wg >> 3);
  const int m0  = (sw & 15) * 256;
  const int rn0 = (sw >> 4) * 384;

  const unsigned short* Ag = Xb + (size_t)m0 * HID;

  // staging: one STG = 512 lanes x 16B = 8 KiB = one 64-row panel; LDS dest linear,
  // global source chunk pre-swizzled (inverse of frag()'s read swizzle)
  const int sr  = tid >> 3;                    // local row 0..63 in panel
  const int scs = ((tid & 7) ^ (sr & 7)) * 8;  // swizzled source chunk offset (ushorts)

#define STGA(UB, RB, KT)                                              \
  async16(Ag + (size_t)((RB) + sr) * HID + (KT) + scs,                \
          (char*)smem + (size_t)(UB) * 2 + ((RB) * 8 + w * 64) * 16)
#define STGB(UB, RB, KT)                                              \
  async16(Bgp + (size_t)((RB) + sr) * HID + (KT) + scs,               \
          (char*)smem + (size_t)(UB) * 2 + 32768 + ((RB) * 8 + w * 64) * 16)

#define VM6  asm volatile("s_waitcnt vmcnt(6)" ::: "memory")
#define VM0  asm volatile("s_waitcnt vmcnt(0)" ::: "memory")

#define PHASE(UB, KK, STGBLK, WAITBLK)                                         \
  {                                                                            \
    const unsigned short* Ab = smem + (UB);                                    \
    const unsigned short* Bb = Ab + 16384;                                     \
    bf16x8 ta[8], tb[2];                                                       \
    _Pragma("unroll")                                                          \
    for (int ii = 0; ii < 8; ++ii) ta[ii] = frag(Ab, wm + ii * 16 + l16, (KK) * 4 + quad); \
    _Pragma("unroll")                                                          \
    for (int j = 0; j < 2; ++j)  tb[j] = frag(Bb, wn + j * 16 + l16, (KK) * 4 + quad);     \
    STGBLK;                                                                    \
    __builtin_amdgcn_s_barrier();                                              \
    asm volatile("s_waitcnt lgkmcnt(0)" ::: "memory");                         \
    __builtin_amdgcn_s_setprio(1);                                             \
    _Pragma("unroll")                                                          \
    for (int ii = 0; ii < 8; ++ii)                                             \
      _Pragma("unroll")                                                        \
      for (int j = 0; j < 2; ++j) mfma16(acc[ii][j], ta[ii], tb[j]);           \
    __builtin_amdgcn_s_setprio(0);                                             \
    WAITBLK;                                                                   \
    __builtin_amdgcn_s_barrier();                                              \
  }

  for (int p = 0; p < 3; ++p) {
    const unsigned short* Bgp = Wb + (size_t)(rn0 + p * 128) * HID;

    f32x4 acc[8][2];
    const f32x4 zero = {0.f, 0.f, 0.f, 0.f};
#pragma unroll
    for (int a = 0; a < 8; ++a) { acc[a][0] = zero; acc[a][1] = zero; }

    // prologue: t0 -> buf0, t1 -> buf1 (6 loads each); drain t0, leave t1 in flight
    STGA(0, 0, 0);  STGA(0, 64, 0);  STGA(0, 128, 0);  STGA(0, 192, 0);
    STGB(0, 0, 0);  STGB(0, 64, 0);
    STGA(BUFU, 0, 64);  STGA(BUFU, 64, 64);  STGA(BUFU, 128, 64);  STGA(BUFU, 192, 64);
    STGB(BUFU, 0, 64);  STGB(BUFU, 64, 64);
    VM6;
    __builtin_amdgcn_s_barrier();

    // buffer offsets (ushorts): tile t lives in buffer (t % 3)
    int ube = 0, ubo = BUFU;           // buffers of tiles 2i, 2i+1
    int nbe = 2 * BUFU, nbo = 0;       // buffers of tiles 2i+2, 2i+3

    for (int i = 0; i < 15; ++i) {
      const int kpe = (2 * i + 2) * 64;   // <= 30*64, no clamp needed
      const int kpo = (2 * i + 3) * 64;   // <= 31*64

      // P1: even tile kk=0 | issue pe A0,A64,A128
      PHASE(ube, 0, { STGA(nbe, 0, kpe); STGA(nbe, 64, kpe); STGA(nbe, 128, kpe); }, {});
      // P2: even tile kk=1 | issue pe A192,B0,B64 | vmcnt(6): odd tile landed for P3
      PHASE(ube, 1, { STGA(nbe, 192, kpe); STGB(nbe, 0, kpe); STGB(nbe, 64, kpe); }, VM6);
      // P3: odd tile kk=0 | issue po A0,A64,A128 (into even buffer, dead after P2)
      PHASE(ubo, 0, { STGA(nbo, 0, kpo); STGA(nbo, 64, kpo); STGA(nbo, 128, kpo); }, {});
      // P4: odd tile kk=1 | issue po A192,B0,B64 | vmcnt(6): pe landed for next P1
      PHASE(ubo, 1, { STGA(nbo, 192, kpo); STGB(nbo, 0, kpo); STGB(nbo, 64, kpo); }, VM6);

      ube = nbe; ubo = nbo;
      nbe = (nbe + 2 * BUFU >= BUF3) ? nbe + 2 * BUFU - BUF3 : nbe + 2 * BUFU;
      nbo = (nbo + 2 * BUFU >= BUF3) ? nbo + 2 * BUFU - BUF3 : nbo + 2 * BUFU;
    }

    // peeled last iteration (tiles 30, 31): no prefetch; vmcnt(0) drains tile 31
    PHASE(ube, 0, {}, {});
    PHASE(ube, 1, {}, VM0);
    PHASE(ubo, 0, {}, {});
    PHASE(ubo, 1, {}, {});

    // pass epilogue: bias + bf16 store of the 256x128 column block
#pragma unroll
    for (int j = 0; j < 2; ++j) {
      int ng = rn0 + p * 128 + wn + j * 16 + l16;
      float bias = (ng < HID) ? bq[ng] : (ng < 2 * HID ? bk[ng - HID] : bv[ng - 2 * HID]);
#pragma unroll
      for (int a = 0; a < 8; ++a)
#pragma unroll
        for (int r = 0; r < 4; ++r) {
          int mg = m0 + wm + a * 16 + quad * 4 + r;
          Cout[(size_t)mg * NQKV + ng] = f2bf(acc[a][j][r] + bias);
        }
    }
  }
#undef STGA
#undef STGB
#undef PHASE
#undef VM6
#undef VM0
}

// ---------------- GEMM 2: out-proj + bias + residual, fp32 out ----------------
__global__ __launch_bounds__(256) void gemm_out_kernel(
    const unsigned short* __restrict__ Ctx, const unsigned short* __restrict__ Wdb,
    const float* __restrict__ bd, const float* __restrict__ Res,
    float* __restrict__ Out) {
  __shared__ __align__(16) unsigned short As[128 * 64];
  __shared__ __align__(16) unsigned short Bs[128 * 64];
  f32x4 acc[4][4];
  const int m0 = blockIdx.y * 128, n0 = blockIdx.x * 128;
  gemm_core(Ctx, Wdb, HID, m0, n0, As, Bs, acc);

  const int tid = threadIdx.x, w = tid >> 6, lane = tid & 63;
  const int l16 = lane & 15, quad = lane >> 4;
  const int wm = (w & 1) * 64, wn = (w >> 1) * 64;
#pragma unroll
  for (int j = 0; j < 4; ++j) {
    int ng = n0 + wn + j * 16 + l16;
    float bias = bd[ng];
#pragma unroll
    for (int i = 0; i < 4; ++i)
#pragma unroll
      for (int r = 0; r < 4; ++r) {
        int mg = m0 + wm + i * 16 + quad * 4 + r;
        size_t off = (size_t)mg * HID + ng;
        Out[off] = acc[i][j][r] + bias + Res[off];
      }
  }
}

// ---------------- V transpose: QKV V-part -> Vt[bh][d][s] ----------------
__global__ __launch_bounds__(256) void vtrans_kernel(const unsigned short* __restrict__ QKV,
                                                     unsigned short* __restrict__ Vt) {
  __shared__ __align__(16) unsigned short T[64][72];
  const int s0 = blockIdx.x * 64, d0 = blockIdx.y * 64, bh = blockIdx.z;
  const int b = bh >> 4, h = bh & 15;
  const int tid = threadIdx.x;
#pragma unroll
  for (int i = 0; i < 2; ++i) {
    int idx = i * 256 + tid;
    int r = idx >> 3, ch = idx & 7;
    const unsigned short* g = QKV + ((size_t)b * SEQ + s0 + r) * NQKV + 2 * HID + h * HD + d0 + ch * 8;
    *(uint4*)(&T[r][ch * 8]) = *(const uint4*)g;
  }
  __syncthreads();
#pragma unroll
  for (int i = 0; i < 2; ++i) {
    int idx = i * 256 + tid;
    int d = idx >> 3, ch = idx & 7;
    unsigned short v[8];
#pragma unroll
    for (int x = 0; x < 8; ++x) v[x] = T[ch * 8 + x][d];
    unsigned short* g = Vt + ((size_t)bh * HD + d0 + d) * SEQ + s0 + ch * 8;
    *(uint4*)g = *(const uint4*)v;
  }
}

// ---------------- flash attention, 32x32 MFMA, S^T trick ----------------
// grid = (SEQ/128, BATCH*NHEAD); block 256 (4 waves, each 32 q-rows)
__global__ __launch_bounds__(256, 2) void attn_kernel(
    const unsigned short* __restrict__ QKV, const unsigned short* __restrict__ Vt,
    const float* __restrict__ alibi, unsigned short* __restrict__ Ctx) {
  __shared__ __align__(16) char smem[51200];
  unsigned short* Ks  = (unsigned short*)smem;
  unsigned short* Vts = (unsigned short*)(smem + 16384);
  unsigned short* Ps  = (unsigned short*)(smem + 32768);
  unsigned short* Qs  = (unsigned short*)smem;          // alias: Q staging (32 KB)

  const int tid = threadIdx.x, w = tid >> 6, lane = tid & 63;
  const int l32 = lane & 31, h = lane >> 5;
  const int q0 = blockIdx.x * 128;
  const int bh = blockIdx.y, b = bh >> 4, hh = bh & 15;
  const size_t rowbase = (size_t)b * SEQ;
  const float* ali = alibi + (size_t)bh * SEQ;
  const unsigned short* Vbh = Vt + (size_t)bh * HD * SEQ;

  {
    const unsigned short* qbase = QKV + (rowbase + q0) * NQKV + hh * HD;
#pragma unroll
    for (int i = 0; i < 8; ++i) {
      int slot = i * 256 + w * 64 + lane;
      int r = slot >> 4, c = (slot & 15) ^ (r & 15);
      async16(qbase + (size_t)r * NQKV + c * 8, (char*)Qs + (size_t)(i * 256 + w * 64) * 16);
    }
  }
  __syncthreads();
  bf16x8 qf[8];
  {
    int qr = w * 32 + l32;
#pragma unroll
    for (int ks = 0; ks < 8; ++ks) {
      int c = (ks * 2 + h) ^ (qr & 15);
      qf[ks] = *(const bf16x8*)(Qs + (qr * 16 + c) * 8);
    }
  }

  f32x16 oacc[4];
  float l_acc = 0.f;
#pragma unroll
  for (int nb = 0; nb < 4; ++nb)
#pragma unroll
    for (int r = 0; r < 16; ++r) oacc[nb][r] = 0.f;

  __syncthreads();

  for (int kt = 0; kt < SEQ / 64; ++kt) {
    {
      const unsigned short* kbase = QKV + (rowbase + kt * 64) * NQKV + HID + hh * HD;
#pragma unroll
      for (int i = 0; i < 4; ++i) {
        int slot = i * 256 + w * 64 + lane;
        int r = slot >> 4, c = (slot & 15) ^ (r & 15);
        async16(kbase + (size_t)r * NQKV + c * 8, (char*)Ks + (size_t)(i * 256 + w * 64) * 16);
      }
      const unsigned short* vbase = Vbh + kt * 64;
#pragma unroll
      for (int i = 0; i < 4; ++i) {
        int slot = i * 256 + w * 64 + lane;
        int r = slot >> 3, c = (slot & 7) ^ (r & 7);
        async16(vbase + (size_t)r * SEQ + c * 8, (char*)Vts + (size_t)(i * 256 + w * 64) * 16);
      }
    }
    __syncthreads();

    f32x16 sacc[2];
#pragma unroll
    for (int mb = 0; mb < 2; ++mb)
#pragma unroll
      for (int r = 0; r < 16; ++r) sacc[mb][r] = 0.f;
#pragma unroll
    for (int ks = 0; ks < 8; ++ks) {
#pragma unroll
      for (int mb = 0; mb < 2; ++mb) {
        bf16x8 kf = *(const bf16x8*)(Ks + ((mb * 32 + l32) * 16 + ((ks * 2 + h) ^ (l32 & 15))) * 8);
        sacc[mb] = __builtin_amdgcn_mfma_f32_32x32x16_bf16(kf, qf[ks], sacc[mb], 0, 0, 0);
      }
    }

    const float* alik = ali + kt * 64 + 4 * h;
    const int qrow = w * 32 + l32;
#pragma unroll
    for (int mb = 0; mb < 2; ++mb) {
#pragma unroll
      for (int g = 0; g < 4; ++g) {
        float4 av = *(const float4*)(alik + mb * 32 + g * 8);
        float p0 = __builtin_amdgcn_exp2f(sacc[mb][g * 4 + 0] * SCALE_L2 + av.x * LOG2E);
        float p1 = __builtin_amdgcn_exp2f(sacc[mb][g * 4 + 1] * SCALE_L2 + av.y * LOG2E);
        float p2 = __builtin_amdgcn_exp2f(sacc[mb][g * 4 + 2] * SCALE_L2 + av.z * LOG2E);
        float p3 = __builtin_amdgcn_exp2f(sacc[mb][g * 4 + 3] * SCALE_L2 + av.w * LOG2E);
        l_acc += (p0 + p1) + (p2 + p3);
        uint2 pk;
        pk.x = pkbf(p0, p1);
        pk.y = pkbf(p2, p3);
        *(uint2*)(Ps + qrow * 72 + mb * 32 + g * 8 + 4 * h) = pk;
      }
    }

#pragma unroll
    for (int ks2 = 0; ks2 < 4; ++ks2) {
      bf16x8 pf = *(const bf16x8*)(Ps + qrow * 72 + ks2 * 16 + h * 8);
#pragma unroll
      for (int nb = 0; nb < 4; ++nb) {
        bf16x8 vf = *(const bf16x8*)(Vts + ((nb * 32 + l32) * 8 + ((ks2 * 2 + h) ^ (l32 & 7))) * 8);
        oacc[nb] = __builtin_amdgcn_mfma_f32_32x32x16_bf16(pf, vf, oacc[nb], 0, 0, 0);
      }
    }
    __syncthreads();
  }

  float lf = l_acc + __shfl_xor(l_acc, 32, 64);
  float rinv[16];
#pragma unroll
  for (int reg = 0; reg < 16; ++reg) {
    int row = (reg & 3) + 8 * (reg >> 2) + 4 * h;
    rinv[reg] = 1.0f / __shfl(lf, row, 64);
  }

#pragma unroll
  for (int nb = 0; nb < 4; ++nb)
#pragma unroll
    for (int reg = 0; reg < 16; ++reg) {
      int row = (reg & 3) + 8 * (reg >> 2) + 4 * h;
      size_t qg = rowbase + q0 + w * 32 + row;
      Ctx[qg * HID + hh * HD + nb * 32 + l32] = f2bf(oacc[nb][reg] * rinv[reg]);
    }
}

// ---------------- launch ----------------
extern "C" void kernel_launch(void* const* d_in, const int* in_sizes, int n_in,
                              void* d_out, int out_size, void* d_ws, size_t ws_size,
                              hipStream_t stream) {
  const float* hidden   = (const float*)d_in[0];
  const float* residual = (const float*)d_in[1];
  const float* alibi    = (const float*)d_in[2];
  const float* Wq = (const float*)d_in[3];
  const float* bq = (const float*)d_in[4];
  const float* Wk = (const float*)d_in[5];
  const float* bk = (const float*)d_in[6];
  const float* Wv = (const float*)d_in[7];
  const float* bv = (const float*)d_in[8];
  const float* Wd = (const float*)d_in[9];
  const float* bd = (const float*)d_in[10];
  float* out = (float*)d_out;

  unsigned short* Xb    = (unsigned short*)d_ws;                    // 4096*2048
  unsigned short* Wqkvb = Xb + (size_t)MROWS * HID;                 // 6144*2048
  unsigned short* Wdb   = Wqkvb + (size_t)NQKV * HID;               // 2048*2048
  unsigned short* QKVb  = Wdb + (size_t)HID * HID;                  // 4096*6144
  unsigned short* Ctxb  = QKVb + (size_t)MROWS * NQKV;              // 4096*2048
  unsigned short* Vtb   = Wqkvb;  // Vt reuses Wqkvb region (dead after gemm_qkv)

  const int nX = MROWS * HID, nW = HID * HID;
  cvt_kernel<<<nX / 4 / 256, 256, 0, stream>>>(hidden, Xb, nX);
  cvtw_kernel<<<dim3(nW / 4 / 256, 4), 256, 0, stream>>>(Wq, Wk, Wv, Wd, Wqkvb);

  gemm_qkv384_kernel<<<256, 512, 0, stream>>>(Xb, Wqkvb, bq, bk, bv, QKVb);
  vtrans_kernel<<<dim3(SEQ / 64, HD / 64, BATCH * NHEAD), 256, 0, stream>>>(QKVb, Vtb);
  attn_kernel<<<dim3(SEQ / 128, BATCH * NHEAD), 256, 0, stream>>>(QKVb, Vtb, alibi, Ctxb);
  gemm_out_kernel<<<dim3(HID / 128, MROWS / 128), 256, 0, stream>>>(Ctxb, Wdb, bd, residual, out);
}

// Round 4
// 447.901 us; speedup vs baseline: 1.0626x; 1.0025x over previous
//
#include <hip/hip_runtime.h>

// ---------------- problem constants ----------------
#define HID   2048
#define NHEAD 16
#define HD    128
#define SEQ   2048
#define BATCH 2
#define MROWS (BATCH*SEQ)        // 4096
#define NQKV  (3*HID)            // 6144
#define INV_NORM 0.08838834764831845f
#define LOG2E    1.4426950408889634f
#define SCALE_L2 (INV_NORM*LOG2E)

typedef __attribute__((ext_vector_type(8)))  __bf16 bf16x8;
typedef __attribute__((ext_vector_type(4)))  float  f32x4;
typedef __attribute__((ext_vector_type(16))) float  f32x16;

typedef __attribute__((address_space(1))) void GV;
typedef __attribute__((address_space(3))) void LV;

__device__ __forceinline__ void async16(const void* g, void* l) {
  __builtin_amdgcn_global_load_lds((const GV*)g, (LV*)l, 16, 0, 0);
}

__device__ __forceinline__ unsigned short f2bf(float f) {
  unsigned u = __builtin_bit_cast(unsigned, f);
  u += 0x7FFFu + ((u >> 16) & 1u);       // RNE
  return (unsigned short)(u >> 16);
}

__device__ __forceinline__ unsigned pkbf(float a, float b) {
#if __has_builtin(__builtin_amdgcn_cvt_pk_bf16_f32)
  typedef __attribute__((ext_vector_type(2))) __bf16 bf16x2;
  bf16x2 r = __builtin_amdgcn_cvt_pk_bf16_f32(a, b);
  return __builtin_bit_cast(unsigned, r);
#else
  return (unsigned)f2bf(a) | ((unsigned)f2bf(b) << 16);
#endif
}

__device__ __forceinline__ void mfma16(f32x4& c, bf16x8 a, bf16x8 b) {
  c = __builtin_amdgcn_mfma_f32_16x16x32_bf16(a, b, c, 0, 0, 0);
}

// LDS fragment read with chunk-XOR swizzle (BK=64 -> 8 chunks of 16B per row)
__device__ __forceinline__ bf16x8 frag(const unsigned short* buf, int row, int chunk) {
  return *(const bf16x8*)(buf + ((row * 8 + (chunk ^ (row & 7))) << 3));
}

// ---------------- fp32 -> bf16 casts ----------------
__global__ __launch_bounds__(256) void cvt_kernel(const float* __restrict__ src,
                                                  unsigned short* __restrict__ dst, int n) {
  int i = (blockIdx.x * 256 + threadIdx.x) * 4;
  if (i >= n) return;
  float4 v = *(const float4*)(src + i);
  ushort4 o;
  o.x = f2bf(v.x); o.y = f2bf(v.y); o.z = f2bf(v.z); o.w = f2bf(v.w);
  *(ushort4*)(dst + i) = o;
}

__global__ __launch_bounds__(256) void cvtw_kernel(const float* __restrict__ W0,
                                                   const float* __restrict__ W1,
                                                   const float* __restrict__ W2,
                                                   const float* __restrict__ W3,
                                                   unsigned short* __restrict__ dst) {
  int sel = blockIdx.y;
  const float* src = (sel == 0) ? W0 : (sel == 1) ? W1 : (sel == 2) ? W2 : W3;
  unsigned short* d = dst + (size_t)sel * HID * HID;
  int i = (blockIdx.x * 256 + threadIdx.x) * 4;
  float4 v = *(const float4*)(src + i);
  ushort4 o;
  o.x = f2bf(v.x); o.y = f2bf(v.y); o.z = f2bf(v.z); o.w = f2bf(v.w);
  *(ushort4*)(d + i) = o;
}

// ---------------- 128x128 NT GEMM core (kept for gemm_out) ----------------
__device__ __forceinline__ void gemm_core(const unsigned short* __restrict__ A,
                                          const unsigned short* __restrict__ Bm,
                                          int K, int m0, int n0,
                                          unsigned short* As, unsigned short* Bs,
                                          f32x4 (&acc)[4][4]) {
  const int tid  = threadIdx.x;
  const int w    = tid >> 6;
  const int lane = tid & 63;
  const int l16  = lane & 15;
  const int quad = lane >> 4;
  const int wm   = (w & 1) * 64;
  const int wn   = (w >> 1) * 64;

  const f32x4 zero = {0.f, 0.f, 0.f, 0.f};
#pragma unroll
  for (int i = 0; i < 4; ++i)
#pragma unroll
    for (int j = 0; j < 4; ++j) acc[i][j] = zero;

  for (int k0 = 0; k0 < K; k0 += 64) {
    __syncthreads();
#pragma unroll
    for (int i = 0; i < 4; ++i) {
      int slot = i * 256 + w * 64 + lane;
      int r = slot >> 3;
      int c = (slot & 7) ^ (r & 7);
      async16(A  + (size_t)(m0 + r) * K + k0 + c * 8, (char*)As + (size_t)(i * 256 + w * 64) * 16);
      async16(Bm + (size_t)(n0 + r) * K + k0 + c * 8, (char*)Bs + (size_t)(i * 256 + w * 64) * 16);
    }
    __syncthreads();

#pragma unroll
    for (int kk = 0; kk < 2; ++kk) {
      bf16x8 af[4], bfp[4];
#pragma unroll
      for (int i = 0; i < 4; ++i) af[i]  = frag(As, wm + i * 16 + l16, kk * 4 + quad);
#pragma unroll
      for (int j = 0; j < 4; ++j) bfp[j] = frag(Bs, wn + j * 16 + l16, kk * 4 + quad);
#pragma unroll
      for (int i = 0; i < 4; ++i)
#pragma unroll
        for (int j = 0; j < 4; ++j) mfma16(acc[i][j], af[i], bfp[j]);
    }
  }
}

// ---------------- GEMM 1: QKV projection, persistent 256-block, 3x(256x128) passes ----
// Grid = 256 blocks (EXACT 1 round on 256 CUs, uniform work -> zero tail).
// Each block owns a 256x384 region = 3 passes of 256x128 (A re-read from L2 per pass).
// 512 thr = 8 waves (4M x 2N); per-wave 64x64; acc[4][4] (64 VGPR); BK=64.
//   4Mx2N (square per-wave tile) minimizes per-wave row-span (64+64=128 vs 128+32=160)
//   -> 8 ds_read_b128 per 16-MFMA phase (was 10), -20% LDS read traffic.
// LDS: 3 rotating buffers x (A 256x64 + B 128x64) = 3 x 48KB = 144KB.
// FIFO-verified waits: vmcnt(6) at end-P2 (drains odd tile) and end-P4 (drains next
// even tile); every waited load issued 3-4 phases earlier; >=6 in flight except the
// peeled last iteration per pass (one vmcnt(0)).
#define BUFU (24576)   // ushorts per buffer (48KB): A 16384 + B 8192
#define BUF3 (3 * BUFU)

__global__ __launch_bounds__(512, 2) void gemm_qkv384_kernel(
    const unsigned short* __restrict__ Xb, const unsigned short* __restrict__ Wb,
    const float* __restrict__ bq, const float* __restrict__ bk,
    const float* __restrict__ bv, unsigned short* __restrict__ Cout) {
  __shared__ __align__(16) unsigned short smem[BUF3];   // 144 KiB

  const int tid  = threadIdx.x;
  const int w    = tid >> 6;
  const int lane = tid & 63;
  const int l16  = lane & 15;
  const int quad = lane >> 4;
  const int wm   = (w & 3) * 64;    // 4 M-waves
  const int wn   = (w >> 2) * 64;   // 2 N-waves

  // XCD-swizzled region mapping; grid = 256 = 16(m) x 16(n-region), 256 % 8 == 0
  const int wg = blockIdx.x;
  const int sw = (wg & 7) * 32 + (wg >> 3);
  const int m0  = (sw & 15) * 256;
  const int rn0 = (sw >> 4) * 384;

  const unsigned short* Ag = Xb + (size_t)m0 * HID;

  // staging: one STG = 512 lanes x 16B = 8 KiB = one 64-row panel; LDS dest linear,
  // global source chunk pre-swizzled (inverse of frag()'s read swizzle)
  const int sr  = tid >> 3;                    // local row 0..63 in panel
  const int scs = ((tid & 7) ^ (sr & 7)) * 8;  // swizzled source chunk offset (ushorts)

#define STGA(UB, RB, KT)                                              \
  async16(Ag + (size_t)((RB) + sr) * HID + (KT) + scs,                \
          (char*)smem + (size_t)(UB) * 2 + ((RB) * 8 + w * 64) * 16)
#define STGB(UB, RB, KT)                                              \
  async16(Bgp + (size_t)((RB) + sr) * HID + (KT) + scs,               \
          (char*)smem + (size_t)(UB) * 2 + 32768 + ((RB) * 8 + w * 64) * 16)

#define VM6  asm volatile("s_waitcnt vmcnt(6)" ::: "memory")
#define VM0  asm volatile("s_waitcnt vmcnt(0)" ::: "memory")

#define PHASE(UB, KK, STGBLK, WAITBLK)                                         \
  {                                                                            \
    const unsigned short* Ab = smem + (UB);                                    \
    const unsigned short* Bb = Ab + 16384;                                     \
    bf16x8 ta[4], tb[4];                                                       \
    _Pragma("unroll")                                                          \
    for (int ii = 0; ii < 4; ++ii) ta[ii] = frag(Ab, wm + ii * 16 + l16, (KK) * 4 + quad); \
    _Pragma("unroll")                                                          \
    for (int j = 0; j < 4; ++j)  tb[j] = frag(Bb, wn + j * 16 + l16, (KK) * 4 + quad);     \
    STGBLK;                                                                    \
    __builtin_amdgcn_s_barrier();                                              \
    asm volatile("s_waitcnt lgkmcnt(0)" ::: "memory");                         \
    __builtin_amdgcn_s_setprio(1);                                             \
    _Pragma("unroll")                                                          \
    for (int ii = 0; ii < 4; ++ii)                                             \
      _Pragma("unroll")                                                        \
      for (int j = 0; j < 4; ++j) mfma16(acc[ii][j], ta[ii], tb[j]);           \
    __builtin_amdgcn_s_setprio(0);                                             \
    WAITBLK;                                                                   \
    __builtin_amdgcn_s_barrier();                                              \
  }

  for (int p = 0; p < 3; ++p) {
    const unsigned short* Bgp = Wb + (size_t)(rn0 + p * 128) * HID;

    f32x4 acc[4][4];
    const f32x4 zero = {0.f, 0.f, 0.f, 0.f};
#pragma unroll
    for (int a = 0; a < 4; ++a)
#pragma unroll
      for (int j = 0; j < 4; ++j) acc[a][j] = zero;

    // prologue: t0 -> buf0, t1 -> buf1 (6 loads each); drain t0, leave t1 in flight
    STGA(0, 0, 0);  STGA(0, 64, 0);  STGA(0, 128, 0);  STGA(0, 192, 0);
    STGB(0, 0, 0);  STGB(0, 64, 0);
    STGA(BUFU, 0, 64);  STGA(BUFU, 64, 64);  STGA(BUFU, 128, 64);  STGA(BUFU, 192, 64);
    STGB(BUFU, 0, 64);  STGB(BUFU, 64, 64);
    VM6;
    __builtin_amdgcn_s_barrier();

    // buffer offsets (ushorts): tile t lives in buffer (t % 3)
    int ube = 0, ubo = BUFU;           // buffers of tiles 2i, 2i+1
    int nbe = 2 * BUFU, nbo = 0;       // buffers of tiles 2i+2, 2i+3

    for (int i = 0; i < 15; ++i) {
      const int kpe = (2 * i + 2) * 64;   // <= 30*64, no clamp needed
      const int kpo = (2 * i + 3) * 64;   // <= 31*64

      // P1: even tile kk=0 | issue pe A0,A64,A128
      PHASE(ube, 0, { STGA(nbe, 0, kpe); STGA(nbe, 64, kpe); STGA(nbe, 128, kpe); }, {});
      // P2: even tile kk=1 | issue pe A192,B0,B64 | vmcnt(6): odd tile landed for P3
      PHASE(ube, 1, { STGA(nbe, 192, kpe); STGB(nbe, 0, kpe); STGB(nbe, 64, kpe); }, VM6);
      // P3: odd tile kk=0 | issue po A0,A64,A128 (into even buffer, dead after P2)
      PHASE(ubo, 0, { STGA(nbo, 0, kpo); STGA(nbo, 64, kpo); STGA(nbo, 128, kpo); }, {});
      // P4: odd tile kk=1 | issue po A192,B0,B64 | vmcnt(6): pe landed for next P1
      PHASE(ubo, 1, { STGA(nbo, 192, kpo); STGB(nbo, 0, kpo); STGB(nbo, 64, kpo); }, VM6);

      ube = nbe; ubo = nbo;
      nbe = (nbe + 2 * BUFU >= BUF3) ? nbe + 2 * BUFU - BUF3 : nbe + 2 * BUFU;
      nbo = (nbo + 2 * BUFU >= BUF3) ? nbo + 2 * BUFU - BUF3 : nbo + 2 * BUFU;
    }

    // peeled last iteration (tiles 30, 31): no prefetch; vmcnt(0) drains tile 31
    PHASE(ube, 0, {}, {});
    PHASE(ube, 1, {}, VM0);
    PHASE(ubo, 0, {}, {});
    PHASE(ubo, 1, {}, {});

    // pass epilogue: bias + bf16 store of the 256x128 column block
#pragma unroll
    for (int j = 0; j < 4; ++j) {
      int ng = rn0 + p * 128 + wn + j * 16 + l16;
      float bias = (ng < HID) ? bq[ng] : (ng < 2 * HID ? bk[ng - HID] : bv[ng - 2 * HID]);
#pragma unroll
      for (int a = 0; a < 4; ++a)
#pragma unroll
        for (int r = 0; r < 4; ++r) {
          int mg = m0 + wm + a * 16 + quad * 4 + r;
          Cout[(size_t)mg * NQKV + ng] = f2bf(acc[a][j][r] + bias);
        }
    }
  }
#undef STGA
#undef STGB
#undef PHASE
#undef VM6
#undef VM0
}

// ---------------- GEMM 2: out-proj + bias + residual, fp32 out ----------------
__global__ __launch_bounds__(256) void gemm_out_kernel(
    const unsigned short* __restrict__ Ctx, const unsigned short* __restrict__ Wdb,
    const float* __restrict__ bd, const float* __restrict__ Res,
    float* __restrict__ Out) {
  __shared__ __align__(16) unsigned short As[128 * 64];
  __shared__ __align__(16) unsigned short Bs[128 * 64];
  f32x4 acc[4][4];
  const int m0 = blockIdx.y * 128, n0 = blockIdx.x * 128;
  gemm_core(Ctx, Wdb, HID, m0, n0, As, Bs, acc);

  const int tid = threadIdx.x, w = tid >> 6, lane = tid & 63;
  const int l16 = lane & 15, quad = lane >> 4;
  const int wm = (w & 1) * 64, wn = (w >> 1) * 64;
#pragma unroll
  for (int j = 0; j < 4; ++j) {
    int ng = n0 + wn + j * 16 + l16;
    float bias = bd[ng];
#pragma unroll
    for (int i = 0; i < 4; ++i)
#pragma unroll
      for (int r = 0; r < 4; ++r) {
        int mg = m0 + wm + i * 16 + quad * 4 + r;
        size_t off = (size_t)mg * HID + ng;
        Out[off] = acc[i][j][r] + bias + Res[off];
      }
  }
}

// ---------------- V transpose: QKV V-part -> Vt[bh][d][s] ----------------
__global__ __launch_bounds__(256) void vtrans_kernel(const unsigned short* __restrict__ QKV,
                                                     unsigned short* __restrict__ Vt) {
  __shared__ __align__(16) unsigned short T[64][72];
  const int s0 = blockIdx.x * 64, d0 = blockIdx.y * 64, bh = blockIdx.z;
  const int b = bh >> 4, h = bh & 15;
  const int tid = threadIdx.x;
#pragma unroll
  for (int i = 0; i < 2; ++i) {
    int idx = i * 256 + tid;
    int r = idx >> 3, ch = idx & 7;
    const unsigned short* g = QKV + ((size_t)b * SEQ + s0 + r) * NQKV + 2 * HID + h * HD + d0 + ch * 8;
    *(uint4*)(&T[r][ch * 8]) = *(const uint4*)g;
  }
  __syncthreads();
#pragma unroll
  for (int i = 0; i < 2; ++i) {
    int idx = i * 256 + tid;
    int d = idx >> 3, ch = idx & 7;
    unsigned short v[8];
#pragma unroll
    for (int x = 0; x < 8; ++x) v[x] = T[ch * 8 + x][d];
    unsigned short* g = Vt + ((size_t)bh * HD + d0 + d) * SEQ + s0 + ch * 8;
    *(uint4*)g = *(const uint4*)v;
  }
}

// ---------------- flash attention, 32x32 MFMA, S^T trick ----------------
// grid = (SEQ/128, BATCH*NHEAD); block 256 (4 waves, each 32 q-rows)
__global__ __launch_bounds__(256, 2) void attn_kernel(
    const unsigned short* __restrict__ QKV, const unsigned short* __restrict__ Vt,
    const float* __restrict__ alibi, unsigned short* __restrict__ Ctx) {
  __shared__ __align__(16) char smem[51200];
  unsigned short* Ks  = (unsigned short*)smem;
  unsigned short* Vts = (unsigned short*)(smem + 16384);
  unsigned short* Ps  = (unsigned short*)(smem + 32768);
  unsigned short* Qs  = (unsigned short*)smem;          // alias: Q staging (32 KB)

  const int tid = threadIdx.x, w = tid >> 6, lane = tid & 63;
  const int l32 = lane & 31, h = lane >> 5;
  const int q0 = blockIdx.x * 128;
  const int bh = blockIdx.y, b = bh >> 4, hh = bh & 15;
  const size_t rowbase = (size_t)b * SEQ;
  const float* ali = alibi + (size_t)bh * SEQ;
  const unsigned short* Vbh = Vt + (size_t)bh * HD * SEQ;

  {
    const unsigned short* qbase = QKV + (rowbase + q0) * NQKV + hh * HD;
#pragma unroll
    for (int i = 0; i < 8; ++i) {
      int slot = i * 256 + w * 64 + lane;
      int r = slot >> 4, c = (slot & 15) ^ (r & 15);
      async16(qbase + (size_t)r * NQKV + c * 8, (char*)Qs + (size_t)(i * 256 + w * 64) * 16);
    }
  }
  __syncthreads();
  bf16x8 qf[8];
  {
    int qr = w * 32 + l32;
#pragma unroll
    for (int ks = 0; ks < 8; ++ks) {
      int c = (ks * 2 + h) ^ (qr & 15);
      qf[ks] = *(const bf16x8*)(Qs + (qr * 16 + c) * 8);
    }
  }

  f32x16 oacc[4];
  float l_acc = 0.f;
#pragma unroll
  for (int nb = 0; nb < 4; ++nb)
#pragma unroll
    for (int r = 0; r < 16; ++r) oacc[nb][r] = 0.f;

  __syncthreads();

  for (int kt = 0; kt < SEQ / 64; ++kt) {
    {
      const unsigned short* kbase = QKV + (rowbase + kt * 64) * NQKV + HID + hh * HD;
#pragma unroll
      for (int i = 0; i < 4; ++i) {
        int slot = i * 256 + w * 64 + lane;
        int r = slot >> 4, c = (slot & 15) ^ (r & 15);
        async16(kbase + (size_t)r * NQKV + c * 8, (char*)Ks + (size_t)(i * 256 + w * 64) * 16);
      }
      const unsigned short* vbase = Vbh + kt * 64;
#pragma unroll
      for (int i = 0; i < 4; ++i) {
        int slot = i * 256 + w * 64 + lane;
        int r = slot >> 3, c = (slot & 7) ^ (r & 7);
        async16(vbase + (size_t)r * SEQ + c * 8, (char*)Vts + (size_t)(i * 256 + w * 64) * 16);
      }
    }
    __syncthreads();

    f32x16 sacc[2];
#pragma unroll
    for (int mb = 0; mb < 2; ++mb)
#pragma unroll
      for (int r = 0; r < 16; ++r) sacc[mb][r] = 0.f;
#pragma unroll
    for (int ks = 0; ks < 8; ++ks) {
#pragma unroll
      for (int mb = 0; mb < 2; ++mb) {
        bf16x8 kf = *(const bf16x8*)(Ks + ((mb * 32 + l32) * 16 + ((ks * 2 + h) ^ (l32 & 15))) * 8);
        sacc[mb] = __builtin_amdgcn_mfma_f32_32x32x16_bf16(kf, qf[ks], sacc[mb], 0, 0, 0);
      }
    }

    const float* alik = ali + kt * 64 + 4 * h;
    const int qrow = w * 32 + l32;
#pragma unroll
    for (int mb = 0; mb < 2; ++mb) {
#pragma unroll
      for (int g = 0; g < 4; ++g) {
        float4 av = *(const float4*)(alik + mb * 32 + g * 8);
        float p0 = __builtin_amdgcn_exp2f(sacc[mb][g * 4 + 0] * SCALE_L2 + av.x * LOG2E);
        float p1 = __builtin_amdgcn_exp2f(sacc[mb][g * 4 + 1] * SCALE_L2 + av.y * LOG2E);
        float p2 = __builtin_amdgcn_exp2f(sacc[mb][g * 4 + 2] * SCALE_L2 + av.z * LOG2E);
        float p3 = __builtin_amdgcn_exp2f(sacc[mb][g * 4 + 3] * SCALE_L2 + av.w * LOG2E);
        l_acc += (p0 + p1) + (p2 + p3);
        uint2 pk;
        pk.x = pkbf(p0, p1);
        pk.y = pkbf(p2, p3);
        *(uint2*)(Ps + qrow * 72 + mb * 32 + g * 8 + 4 * h) = pk;
      }
    }

#pragma unroll
    for (int ks2 = 0; ks2 < 4; ++ks2) {
      bf16x8 pf = *(const bf16x8*)(Ps + qrow * 72 + ks2 * 16 + h * 8);
#pragma unroll
      for (int nb = 0; nb < 4; ++nb) {
        bf16x8 vf = *(const bf16x8*)(Vts + ((nb * 32 + l32) * 8 + ((ks2 * 2 + h) ^ (l32 & 7))) * 8);
        oacc[nb] = __builtin_amdgcn_mfma_f32_32x32x16_bf16(pf, vf, oacc[nb], 0, 0, 0);
      }
    }
    __syncthreads();
  }

  float lf = l_acc + __shfl_xor(l_acc, 32, 64);
  float rinv[16];
#pragma unroll
  for (int reg = 0; reg < 16; ++reg) {
    int row = (reg & 3) + 8 * (reg >> 2) + 4 * h;
    rinv[reg] = 1.0f / __shfl(lf, row, 64);
  }

#pragma unroll
  for (int nb = 0; nb < 4; ++nb)
#pragma unroll
    for (int reg = 0; reg < 16; ++reg) {
      int row = (reg & 3) + 8 * (reg >> 2) + 4 * h;
      size_t qg = rowbase + q0 + w * 32 + row;
      Ctx[qg * HID + hh * HD + nb * 32 + l32] = f2bf(oacc[nb][reg] * rinv[reg]);
    }
}

// ---------------- launch ----------------
extern "C" void kernel_launch(void* const* d_in, const int* in_sizes, int n_in,
                              void* d_out, int out_size, void* d_ws, size_t ws_size,
                              hipStream_t stream) {
  const float* hidden   = (const float*)d_in[0];
  const float* residual = (const float*)d_in[1];
  const float* alibi    = (const float*)d_in[2];
  const float* Wq = (const float*)d_in[3];
  const float* bq = (const float*)d_in[4];
  const float* Wk = (const float*)d_in[5];
  const float* bk = (const float*)d_in[6];
  const float* Wv = (const float*)d_in[7];
  const float* bv = (const float*)d_in[8];
  const float* Wd = (const float*)d_in[9];
  const float* bd = (const float*)d_in[10];
  float* out = (float*)d_out;

  unsigned short* Xb    = (unsigned short*)d_ws;                    // 4096*2048
  unsigned short* Wqkvb = Xb + (size_t)MROWS * HID;                 // 6144*2048
  unsigned short* Wdb   = Wqkvb + (size_t)NQKV * HID;               // 2048*2048
  unsigned short* QKVb  = Wdb + (size_t)HID * HID;                  // 4096*6144
  unsigned short* Ctxb  = QKVb + (size_t)MROWS * NQKV;              // 4096*2048
  unsigned short* Vtb   = Wqkvb;  // Vt reuses Wqkvb region (dead after gemm_qkv)

  const int nX = MROWS * HID, nW = HID * HID;
  cvt_kernel<<<nX / 4 / 256, 256, 0, stream>>>(hidden, Xb, nX);
  cvtw_kernel<<<dim3(nW / 4 / 256, 4), 256, 0, stream>>>(Wq, Wk, Wv, Wd, Wqkvb);

  gemm_qkv384_kernel<<<256, 512, 0, stream>>>(Xb, Wqkvb, bq, bk, bv, QKVb);
  vtrans_kernel<<<dim3(SEQ / 64, HD / 64, BATCH * NHEAD), 256, 0, stream>>>(QKVb, Vtb);
  attn_kernel<<<dim3(SEQ / 128, BATCH * NHEAD), 256, 0, stream>>>(QKVb, Vtb, alibi, Ctxb);
  gemm_out_kernel<<<dim3(HID / 128, MROWS / 128), 256, 0, stream>>>(Ctxb, Wdb, bd, residual, out);
}

// Round 5
// 437.402 us; speedup vs baseline: 1.0882x; 1.0240x over previous
//
#include <hip/hip_runtime.h>

// ---------------- problem constants ----------------
#define HID   2048
#define NHEAD 16
#define HD    128
#define SEQ   2048
#define BATCH 2
#define MROWS (BATCH*SEQ)        // 4096
#define NQKV  (3*HID)            // 6144
#define INV_NORM 0.08838834764831845f
#define LOG2E    1.4426950408889634f
#define SCALE_L2 (INV_NORM*LOG2E)

typedef __attribute__((ext_vector_type(8)))  __bf16 bf16x8;
typedef __attribute__((ext_vector_type(4)))  float  f32x4;
typedef __attribute__((ext_vector_type(16))) float  f32x16;

typedef __attribute__((address_space(1))) void GV;
typedef __attribute__((address_space(3))) void LV;

__device__ __forceinline__ void async16(const void* g, void* l) {
  __builtin_amdgcn_global_load_lds((const GV*)g, (LV*)l, 16, 0, 0);
}

__device__ __forceinline__ unsigned short f2bf(float f) {
  unsigned u = __builtin_bit_cast(unsigned, f);
  u += 0x7FFFu + ((u >> 16) & 1u);       // RNE
  return (unsigned short)(u >> 16);
}

__device__ __forceinline__ unsigned pkbf(float a, float b) {
#if __has_builtin(__builtin_amdgcn_cvt_pk_bf16_f32)
  typedef __attribute__((ext_vector_type(2))) __bf16 bf16x2;
  bf16x2 r = __builtin_amdgcn_cvt_pk_bf16_f32(a, b);
  return __builtin_bit_cast(unsigned, r);
#else
  return (unsigned)f2bf(a) | ((unsigned)f2bf(b) << 16);
#endif
}

__device__ __forceinline__ void mfma16(f32x4& c, bf16x8 a, bf16x8 b) {
  c = __builtin_amdgcn_mfma_f32_16x16x32_bf16(a, b, c, 0, 0, 0);
}

// LDS fragment read with chunk-XOR swizzle (BK=64 -> 8 chunks of 16B per row)
__device__ __forceinline__ bf16x8 frag(const unsigned short* buf, int row, int chunk) {
  return *(const bf16x8*)(buf + ((row * 8 + (chunk ^ (row & 7))) << 3));
}

// ---------------- fp32 -> bf16 casts ----------------
__global__ __launch_bounds__(256) void cvt_kernel(const float* __restrict__ src,
                                                  unsigned short* __restrict__ dst, int n) {
  int i = (blockIdx.x * 256 + threadIdx.x) * 4;
  if (i >= n) return;
  float4 v = *(const float4*)(src + i);
  ushort4 o;
  o.x = f2bf(v.x); o.y = f2bf(v.y); o.z = f2bf(v.z); o.w = f2bf(v.w);
  *(ushort4*)(dst + i) = o;
}

__global__ __launch_bounds__(256) void cvtw_kernel(const float* __restrict__ W0,
                                                   const float* __restrict__ W1,
                                                   const float* __restrict__ W2,
                                                   const float* __restrict__ W3,
                                                   unsigned short* __restrict__ dst) {
  int sel = blockIdx.y;
  const float* src = (sel == 0) ? W0 : (sel == 1) ? W1 : (sel == 2) ? W2 : W3;
  unsigned short* d = dst + (size_t)sel * HID * HID;
  int i = (blockIdx.x * 256 + threadIdx.x) * 4;
  float4 v = *(const float4*)(src + i);
  ushort4 o;
  o.x = f2bf(v.x); o.y = f2bf(v.y); o.z = f2bf(v.z); o.w = f2bf(v.w);
  *(ushort4*)(d + i) = o;
}

// ---------------- 128x128 NT GEMM core (kept for gemm_out) ----------------
__device__ __forceinline__ void gemm_core(const unsigned short* __restrict__ A,
                                          const unsigned short* __restrict__ Bm,
                                          int K, int m0, int n0,
                                          unsigned short* As, unsigned short* Bs,
                                          f32x4 (&acc)[4][4]) {
  const int tid  = threadIdx.x;
  const int w    = tid >> 6;
  const int lane = tid & 63;
  const int l16  = lane & 15;
  const int quad = lane >> 4;
  const int wm   = (w & 1) * 64;
  const int wn   = (w >> 1) * 64;

  const f32x4 zero = {0.f, 0.f, 0.f, 0.f};
#pragma unroll
  for (int i = 0; i < 4; ++i)
#pragma unroll
    for (int j = 0; j < 4; ++j) acc[i][j] = zero;

  for (int k0 = 0; k0 < K; k0 += 64) {
    __syncthreads();
#pragma unroll
    for (int i = 0; i < 4; ++i) {
      int slot = i * 256 + w * 64 + lane;
      int r = slot >> 3;
      int c = (slot & 7) ^ (r & 7);
      async16(A  + (size_t)(m0 + r) * K + k0 + c * 8, (char*)As + (size_t)(i * 256 + w * 64) * 16);
      async16(Bm + (size_t)(n0 + r) * K + k0 + c * 8, (char*)Bs + (size_t)(i * 256 + w * 64) * 16);
    }
    __syncthreads();

#pragma unroll
    for (int kk = 0; kk < 2; ++kk) {
      bf16x8 af[4], bfp[4];
#pragma unroll
      for (int i = 0; i < 4; ++i) af[i]  = frag(As, wm + i * 16 + l16, kk * 4 + quad);
#pragma unroll
      for (int j = 0; j < 4; ++j) bfp[j] = frag(Bs, wn + j * 16 + l16, kk * 4 + quad);
#pragma unroll
      for (int i = 0; i < 4; ++i)
#pragma unroll
        for (int j = 0; j < 4; ++j) mfma16(acc[i][j], af[i], bfp[j]);
    }
  }
}

// ---------------- GEMM 1: QKV projection, persistent 256-block, 3x(256x128) passes ----
// Grid = 256 blocks (EXACT 1 round on 256 CUs). 512 thr = 8 waves (4M x 2N);
// per-wave 64x64; acc[4][4]; BK=64. LDS: 3 rotating buffers x 48KB = 144KB.
// R5: STATIC buffer rotation (3-iter period fully unrolled -> compile-time LDS
// offsets, hoisted per-lane addresses); ONE barrier per phase; no pre-MFMA
// lgkmcnt(0) (compiler emits staged waits; post-MFMA lgkmcnt(0) = WAR guard).
// Phase: 8 ds_read | 0/3 STG | 8x2 MFMA (staged lgkm) | lgkmcnt(0) | [vmcnt] | barrier.
// FIFO: vmcnt(6) every 2nd phase drains the previous tile-pair's 6 loads.
#define BUFU (24576)   // ushorts per buffer (48KB): A 16384 + B 8192
#define BUF3 (3 * BUFU)

__global__ __launch_bounds__(512, 2) void gemm_qkv384_kernel(
    const unsigned short* __restrict__ Xb, const unsigned short* __restrict__ Wb,
    const float* __restrict__ bq, const float* __restrict__ bk,
    const float* __restrict__ bv, unsigned short* __restrict__ Cout) {
  __shared__ __align__(16) unsigned short smem[BUF3];   // 144 KiB

  const int tid  = threadIdx.x;
  const int w    = tid >> 6;
  const int lane = tid & 63;
  const int l16  = lane & 15;
  const int quad = lane >> 4;
  const int wm   = (w & 3) * 64;    // 4 M-waves
  const int wn   = (w >> 2) * 64;   // 2 N-waves

  // XCD-swizzled region mapping; grid = 256 = 16(m) x 16(n-region)
  const int wg = blockIdx.x;
  const int sw = (wg & 7) * 32 + (wg >> 3);
  const int m0  = (sw & 15) * 256;
  const int rn0 = (sw >> 4) * 384;

  // hoisted per-lane staging bases (row + pre-swizzled chunk)
  const int sr  = tid >> 3;
  const int scs = ((tid & 7) ^ (sr & 7)) * 8;
  const unsigned short* aBase = Xb + (size_t)(m0 + sr) * HID + scs;

// KT and UB are compile-time-affine: UB literal, KT = kb + literal
#define STGA(UB, RB, KT)                                              \
  async16(aBase + (size_t)(RB) * HID + (KT),                          \
          (char*)smem + (UB) * 2 + (RB) * 128 + w * 1024)
#define STGB(UB, RB, KT)                                              \
  async16(bBase + (size_t)(RB) * HID + (KT),                          \
          (char*)smem + (UB) * 2 + 32768 + (RB) * 128 + w * 1024)

#define VM6  asm volatile("s_waitcnt vmcnt(6)" ::: "memory")
#define VM0  asm volatile("s_waitcnt vmcnt(0)" ::: "memory")

// single-barrier phase: reads -> STG issue -> MFMA (compiler-staged lgkm waits)
// -> lgkmcnt(0) (WAR guard) -> optional vmcnt -> barrier
#define PHASE(UB, KK, STGBLK, WAITBLK)                                         \
  {                                                                            \
    const unsigned short* Ab = smem + (UB);                                    \
    const unsigned short* Bb = Ab + 16384;                                     \
    bf16x8 ta[4], tb[4];                                                       \
    ta[0] = frag(Ab, wm + l16, (KK) * 4 + quad);                               \
    _Pragma("unroll")                                                          \
    for (int j = 0; j < 4; ++j)  tb[j] = frag(Bb, wn + j * 16 + l16, (KK) * 4 + quad); \
    _Pragma("unroll")                                                          \
    for (int ii = 1; ii < 4; ++ii) ta[ii] = frag(Ab, wm + ii * 16 + l16, (KK) * 4 + quad); \
    STGBLK;                                                                    \
    __builtin_amdgcn_s_setprio(1);                                             \
    _Pragma("unroll")                                                          \
    for (int ii = 0; ii < 4; ++ii)                                             \
      _Pragma("unroll")                                                        \
      for (int j = 0; j < 4; ++j) mfma16(acc[ii][j], ta[ii], tb[j]);           \
    __builtin_amdgcn_s_setprio(0);                                             \
    asm volatile("s_waitcnt lgkmcnt(0)" ::: "memory");                         \
    WAITBLK;                                                                   \
    __builtin_amdgcn_s_barrier();                                              \
  }

  for (int p = 0; p < 3; ++p) {
    const unsigned short* bBase = Wb + (size_t)(rn0 + p * 128 + sr) * HID + scs;

    f32x4 acc[4][4];
    const f32x4 zero = {0.f, 0.f, 0.f, 0.f};
#pragma unroll
    for (int a = 0; a < 4; ++a)
#pragma unroll
      for (int j = 0; j < 4; ++j) acc[a][j] = zero;

    // prologue: t0 -> buf0, t1 -> buf1 (6 loads each); drain t0, leave t1 in flight
    STGA(0, 0, 0);  STGA(0, 64, 0);  STGA(0, 128, 0);  STGA(0, 192, 0);
    STGB(0, 0, 0);  STGB(0, 64, 0);
    STGA(BUFU, 0, 64);  STGA(BUFU, 64, 64);  STGA(BUFU, 128, 64);  STGA(BUFU, 192, 64);
    STGB(BUFU, 0, 64);  STGB(BUFU, 64, 64);
    VM6;
    __builtin_amdgcn_s_barrier();

    // main loop: 5 groups x 3 iterations (static rotation); tile t -> buffer (t%3)
    int kb = 0;   // = g * 384 (6 tiles of 64 per group)
    for (int g = 0; g < 5; ++g) {
      // i%3==0: compute buf0(even)/buf1(odd); prefetch ->buf2 @kb+128, ->buf0 @kb+192
      PHASE(0,        0, { STGA(2*BUFU, 0, kb+128); STGA(2*BUFU, 64, kb+128); STGA(2*BUFU, 128, kb+128); }, {});
      PHASE(0,        1, { STGA(2*BUFU, 192, kb+128); STGB(2*BUFU, 0, kb+128); STGB(2*BUFU, 64, kb+128); }, VM6);
      PHASE(BUFU,     0, { STGA(0, 0, kb+192); STGA(0, 64, kb+192); STGA(0, 128, kb+192); }, {});
      PHASE(BUFU,     1, { STGA(0, 192, kb+192); STGB(0, 0, kb+192); STGB(0, 64, kb+192); }, VM6);
      // i%3==1: compute buf2/buf0; prefetch ->buf1 @kb+256, ->buf2 @kb+320
      PHASE(2*BUFU,   0, { STGA(BUFU, 0, kb+256); STGA(BUFU, 64, kb+256); STGA(BUFU, 128, kb+256); }, {});
      PHASE(2*BUFU,   1, { STGA(BUFU, 192, kb+256); STGB(BUFU, 0, kb+256); STGB(BUFU, 64, kb+256); }, VM6);
      PHASE(0,        0, { STGA(2*BUFU, 0, kb+320); STGA(2*BUFU, 64, kb+320); STGA(2*BUFU, 128, kb+320); }, {});
      PHASE(0,        1, { STGA(2*BUFU, 192, kb+320); STGB(2*BUFU, 0, kb+320); STGB(2*BUFU, 64, kb+320); }, VM6);
      // i%3==2: compute buf1/buf2; prefetch ->buf0 @kb+384, ->buf1 @kb+448
      PHASE(BUFU,     0, { STGA(0, 0, kb+384); STGA(0, 64, kb+384); STGA(0, 128, kb+384); }, {});
      PHASE(BUFU,     1, { STGA(0, 192, kb+384); STGB(0, 0, kb+384); STGB(0, 64, kb+384); }, VM6);
      PHASE(2*BUFU,   0, { STGA(BUFU, 0, kb+448); STGA(BUFU, 64, kb+448); STGA(BUFU, 128, kb+448); }, {});
      PHASE(2*BUFU,   1, { STGA(BUFU, 192, kb+448); STGB(BUFU, 0, kb+448); STGB(BUFU, 64, kb+448); }, VM6);
      kb += 384;
    }

    // peeled tiles 30 (buf0), 31 (buf1): no prefetch; VM0 drains tile 31's loads
    PHASE(0,    0, {}, {});
    PHASE(0,    1, {}, VM0);
    PHASE(BUFU, 0, {}, {});
    PHASE(BUFU, 1, {}, {});

    // pass epilogue: bias + bf16 store of the 256x128 column block
#pragma unroll
    for (int j = 0; j < 4; ++j) {
      int ng = rn0 + p * 128 + wn + j * 16 + l16;
      float bias = (ng < HID) ? bq[ng] : (ng < 2 * HID ? bk[ng - HID] : bv[ng - 2 * HID]);
#pragma unroll
      for (int a = 0; a < 4; ++a)
#pragma unroll
        for (int r = 0; r < 4; ++r) {
          int mg = m0 + wm + a * 16 + quad * 4 + r;
          Cout[(size_t)mg * NQKV + ng] = f2bf(acc[a][j][r] + bias);
        }
    }
  }
#undef STGA
#undef STGB
#undef PHASE
#undef VM6
#undef VM0
}

// ---------------- GEMM 2: out-proj + bias + residual, fp32 out ----------------
__global__ __launch_bounds__(256) void gemm_out_kernel(
    const unsigned short* __restrict__ Ctx, const unsigned short* __restrict__ Wdb,
    const float* __restrict__ bd, const float* __restrict__ Res,
    float* __restrict__ Out) {
  __shared__ __align__(16) unsigned short As[128 * 64];
  __shared__ __align__(16) unsigned short Bs[128 * 64];
  f32x4 acc[4][4];
  const int m0 = blockIdx.y * 128, n0 = blockIdx.x * 128;
  gemm_core(Ctx, Wdb, HID, m0, n0, As, Bs, acc);

  const int tid = threadIdx.x, w = tid >> 6, lane = tid & 63;
  const int l16 = lane & 15, quad = lane >> 4;
  const int wm = (w & 1) * 64, wn = (w >> 1) * 64;
#pragma unroll
  for (int j = 0; j < 4; ++j) {
    int ng = n0 + wn + j * 16 + l16;
    float bias = bd[ng];
#pragma unroll
    for (int i = 0; i < 4; ++i)
#pragma unroll
      for (int r = 0; r < 4; ++r) {
        int mg = m0 + wm + i * 16 + quad * 4 + r;
        size_t off = (size_t)mg * HID + ng;
        Out[off] = acc[i][j][r] + bias + Res[off];
      }
  }
}

// ---------------- V transpose: QKV V-part -> Vt[bh][d][s] ----------------
__global__ __launch_bounds__(256) void vtrans_kernel(const unsigned short* __restrict__ QKV,
                                                     unsigned short* __restrict__ Vt) {
  __shared__ __align__(16) unsigned short T[64][72];
  const int s0 = blockIdx.x * 64, d0 = blockIdx.y * 64, bh = blockIdx.z;
  const int b = bh >> 4, h = bh & 15;
  const int tid = threadIdx.x;
#pragma unroll
  for (int i = 0; i < 2; ++i) {
    int idx = i * 256 + tid;
    int r = idx >> 3, ch = idx & 7;
    const unsigned short* g = QKV + ((size_t)b * SEQ + s0 + r) * NQKV + 2 * HID + h * HD + d0 + ch * 8;
    *(uint4*)(&T[r][ch * 8]) = *(const uint4*)g;
  }
  __syncthreads();
#pragma unroll
  for (int i = 0; i < 2; ++i) {
    int idx = i * 256 + tid;
    int d = idx >> 3, ch = idx & 7;
    unsigned short v[8];
#pragma unroll
    for (int x = 0; x < 8; ++x) v[x] = T[ch * 8 + x][d];
    unsigned short* g = Vt + ((size_t)bh * HD + d0 + d) * SEQ + s0 + ch * 8;
    *(uint4*)g = *(const uint4*)v;
  }
}

// ---------------- flash attention, 32x32 MFMA, S^T trick ----------------
// grid = (SEQ/128, BATCH*NHEAD); block 256 (4 waves, each 32 q-rows)
__global__ __launch_bounds__(256, 2) void attn_kernel(
    const unsigned short* __restrict__ QKV, const unsigned short* __restrict__ Vt,
    const float* __restrict__ alibi, unsigned short* __restrict__ Ctx) {
  __shared__ __align__(16) char smem[51200];
  unsigned short* Ks  = (unsigned short*)smem;
  unsigned short* Vts = (unsigned short*)(smem + 16384);
  unsigned short* Ps  = (unsigned short*)(smem + 32768);
  unsigned short* Qs  = (unsigned short*)smem;          // alias: Q staging (32 KB)

  const int tid = threadIdx.x, w = tid >> 6, lane = tid & 63;
  const int l32 = lane & 31, h = lane >> 5;
  const int q0 = blockIdx.x * 128;
  const int bh = blockIdx.y, b = bh >> 4, hh = bh & 15;
  const size_t rowbase = (size_t)b * SEQ;
  const float* ali = alibi + (size_t)bh * SEQ;
  const unsigned short* Vbh = Vt + (size_t)bh * HD * SEQ;

  {
    const unsigned short* qbase = QKV + (rowbase + q0) * NQKV + hh * HD;
#pragma unroll
    for (int i = 0; i < 8; ++i) {
      int slot = i * 256 + w * 64 + lane;
      int r = slot >> 4, c = (slot & 15) ^ (r & 15);
      async16(qbase + (size_t)r * NQKV + c * 8, (char*)Qs + (size_t)(i * 256 + w * 64) * 16);
    }
  }
  __syncthreads();
  bf16x8 qf[8];
  {
    int qr = w * 32 + l32;
#pragma unroll
    for (int ks = 0; ks < 8; ++ks) {
      int c = (ks * 2 + h) ^ (qr & 15);
      qf[ks] = *(const bf16x8*)(Qs + (qr * 16 + c) * 8);
    }
  }

  f32x16 oacc[4];
  float l_acc = 0.f;
#pragma unroll
  for (int nb = 0; nb < 4; ++nb)
#pragma unroll
    for (int r = 0; r < 16; ++r) oacc[nb][r] = 0.f;

  __syncthreads();

  for (int kt = 0; kt < SEQ / 64; ++kt) {
    {
      const unsigned short* kbase = QKV + (rowbase + kt * 64) * NQKV + HID + hh * HD;
#pragma unroll
      for (int i = 0; i < 4; ++i) {
        int slot = i * 256 + w * 64 + lane;
        int r = slot >> 4, c = (slot & 15) ^ (r & 15);
        async16(kbase + (size_t)r * NQKV + c * 8, (char*)Ks + (size_t)(i * 256 + w * 64) * 16);
      }
      const unsigned short* vbase = Vbh + kt * 64;
#pragma unroll
      for (int i = 0; i < 4; ++i) {
        int slot = i * 256 + w * 64 + lane;
        int r = slot >> 3, c = (slot & 7) ^ (r & 7);
        async16(vbase + (size_t)r * SEQ + c * 8, (char*)Vts + (size_t)(i * 256 + w * 64) * 16);
      }
    }
    __syncthreads();

    f32x16 sacc[2];
#pragma unroll
    for (int mb = 0; mb < 2; ++mb)
#pragma unroll
      for (int r = 0; r < 16; ++r) sacc[mb][r] = 0.f;
#pragma unroll
    for (int ks = 0; ks < 8; ++ks) {
#pragma unroll
      for (int mb = 0; mb < 2; ++mb) {
        bf16x8 kf = *(const bf16x8*)(Ks + ((mb * 32 + l32) * 16 + ((ks * 2 + h) ^ (l32 & 15))) * 8);
        sacc[mb] = __builtin_amdgcn_mfma_f32_32x32x16_bf16(kf, qf[ks], sacc[mb], 0, 0, 0);
      }
    }

    const float* alik = ali + kt * 64 + 4 * h;
    const int qrow = w * 32 + l32;
#pragma unroll
    for (int mb = 0; mb < 2; ++mb) {
#pragma unroll
      for (int g = 0; g < 4; ++g) {
        float4 av = *(const float4*)(alik + mb * 32 + g * 8);
        float p0 = __builtin_amdgcn_exp2f(sacc[mb][g * 4 + 0] * SCALE_L2 + av.x * LOG2E);
        float p1 = __builtin_amdgcn_exp2f(sacc[mb][g * 4 + 1] * SCALE_L2 + av.y * LOG2E);
        float p2 = __builtin_amdgcn_exp2f(sacc[mb][g * 4 + 2] * SCALE_L2 + av.z * LOG2E);
        float p3 = __builtin_amdgcn_exp2f(sacc[mb][g * 4 + 3] * SCALE_L2 + av.w * LOG2E);
        l_acc += (p0 + p1) + (p2 + p3);
        uint2 pk;
        pk.x = pkbf(p0, p1);
        pk.y = pkbf(p2, p3);
        *(uint2*)(Ps + qrow * 72 + mb * 32 + g * 8 + 4 * h) = pk;
      }
    }

#pragma unroll
    for (int ks2 = 0; ks2 < 4; ++ks2) {
      bf16x8 pf = *(const bf16x8*)(Ps + qrow * 72 + ks2 * 16 + h * 8);
#pragma unroll
      for (int nb = 0; nb < 4; ++nb) {
        bf16x8 vf = *(const bf16x8*)(Vts + ((nb * 32 + l32) * 8 + ((ks2 * 2 + h) ^ (l32 & 7))) * 8);
        oacc[nb] = __builtin_amdgcn_mfma_f32_32x32x16_bf16(pf, vf, oacc[nb], 0, 0, 0);
      }
    }
    __syncthreads();
  }

  float lf = l_acc + __shfl_xor(l_acc, 32, 64);
  float rinv[16];
#pragma unroll
  for (int reg = 0; reg < 16; ++reg) {
    int row = (reg & 3) + 8 * (reg >> 2) + 4 * h;
    rinv[reg] = 1.0f / __shfl(lf, row, 64);
  }

#pragma unroll
  for (int nb = 0; nb < 4; ++nb)
#pragma unroll
    for (int reg = 0; reg < 16; ++reg) {
      int row = (reg & 3) + 8 * (reg >> 2) + 4 * h;
      size_t qg = rowbase + q0 + w * 32 + row;
      Ctx[qg * HID + hh * HD + nb * 32 + l32] = f2bf(oacc[nb][reg] * rinv[reg]);
    }
}

// ---------------- launch ----------------
extern "C" void kernel_launch(void* const* d_in, const int* in_sizes, int n_in,
                              void* d_out, int out_size, void* d_ws, size_t ws_size,
                              hipStream_t stream) {
  const float* hidden   = (const float*)d_in[0];
  const float* residual = (const float*)d_in[1];
  const float* alibi    = (const float*)d_in[2];
  const float* Wq = (const float*)d_in[3];
  const float* bq = (const float*)d_in[4];
  const float* Wk = (const float*)d_in[5];
  const float* bk = (const float*)d_in[6];
  const float* Wv = (const float*)d_in[7];
  const float* bv = (const float*)d_in[8];
  const float* Wd = (const float*)d_in[9];
  const float* bd = (const float*)d_in[10];
  float* out = (float*)d_out;

  unsigned short* Xb    = (unsigned short*)d_ws;                    // 4096*2048
  unsigned short* Wqkvb = Xb + (size_t)MROWS * HID;                 // 6144*2048
  unsigned short* Wdb   = Wqkvb + (size_t)NQKV * HID;               // 2048*2048
  unsigned short* QKVb  = Wdb + (size_t)HID * HID;                  // 4096*6144
  unsigned short* Ctxb  = QKVb + (size_t)MROWS * NQKV;              // 4096*2048
  unsigned short* Vtb   = Wqkvb;  // Vt reuses Wqkvb region (dead after gemm_qkv)

  const int nX = MROWS * HID, nW = HID * HID;
  cvt_kernel<<<nX / 4 / 256, 256, 0, stream>>>(hidden, Xb, nX);
  cvtw_kernel<<<dim3(nW / 4 / 256, 4), 256, 0, stream>>>(Wq, Wk, Wv, Wd, Wqkvb);

  gemm_qkv384_kernel<<<256, 512, 0, stream>>>(Xb, Wqkvb, bq, bk, bv, QKVb);
  vtrans_kernel<<<dim3(SEQ / 64, HD / 64, BATCH * NHEAD), 256, 0, stream>>>(QKVb, Vtb);
  attn_kernel<<<dim3(SEQ / 128, BATCH * NHEAD), 256, 0, stream>>>(QKVb, Vtb, alibi, Ctxb);
  gemm_out_kernel<<<dim3(HID / 128, MROWS / 128), 256, 0, stream>>>(Ctxb, Wdb, bd, residual, out);
}